// Round 1
// baseline (1211.120 us; speedup 1.0000x reference)
//
#include <hip/hip_runtime.h>

#define NN 50000
#define H1 128     // hidden width conv1
#define H2 132     // hidden width conv2 (128 + 4 proj)
#define PROJ 4
#define OUTW 136   // 132 + 4

// ---------------- small utility kernels ----------------

__global__ void k_fill(float* __restrict__ p, int n, float v) {
    int i = blockIdx.x * blockDim.x + threadIdx.x;
    if (i < n) p[i] = v;
}

__global__ void k_zero(float* __restrict__ p, int n) {
    int i = blockIdx.x * blockDim.x + threadIdx.x;
    int stride = gridDim.x * blockDim.x;
    for (; i < n; i += stride) p[i] = 0.0f;
}

__global__ void k_count(const int* __restrict__ col, int E, float* __restrict__ deg) {
    int i = blockIdx.x * blockDim.x + threadIdx.x;
    int stride = gridDim.x * blockDim.x;
    for (; i < E; i += stride) atomicAdd(&deg[col[i]], 1.0f);
}

// degbuf holds deg on entry; on exit degbuf = 1/deg (invdeg), dinv = rsqrt(deg)
__global__ void k_dinv(float* __restrict__ degbuf, float* __restrict__ dinv, int n) {
    int i = blockIdx.x * blockDim.x + threadIdx.x;
    if (i < n) {
        float d = degbuf[i];
        dinv[i]  = rsqrtf(d);
        degbuf[i] = 1.0f / d;
    }
}

// ---------------- FP32 GEMM: out[nrows x ncol] = in[nrows x K] @ W[K x ncol] ----------------
// Block handles ROWS rows; x-tile staged in LDS; W streamed (L1/L2 resident, <70 KB).
#define GROWS 32

__global__ void k_gemm(const float* __restrict__ in, int ldin, int K,
                       const float* __restrict__ W, int ldw, int ncol,
                       float* __restrict__ out, int ldout, int nrows) {
    extern __shared__ float xs[];  // GROWS * K
    int row0 = blockIdx.x * GROWS;
    int tid = threadIdx.x;

    for (int idx = tid; idx < GROWS * K; idx += blockDim.x) {
        int r = idx / K, k = idx - r * K;
        int gr = row0 + r;
        xs[idx] = (gr < nrows) ? in[(size_t)gr * ldin + k] : 0.0f;
    }
    __syncthreads();

    for (int idx = tid; idx < GROWS * ncol; idx += blockDim.x) {
        int r = idx / ncol, c = idx - r * ncol;
        int gr = row0 + r;
        if (gr >= nrows) continue;
        const float* xr = xs + r * K;
        float acc = 0.0f;
#pragma unroll 8
        for (int k = 0; k < K; ++k)
            acc = fmaf(xr[k], W[(size_t)k * ldw + c], acc);
        out[(size_t)gr * ldout + c] = acc;
    }
}

// ---------------- edge scatter: agg[col] += dinv[row]*dinv[col] * h[row] ----------------
// one 64-lane wave per edge (grid-stride over edges)
__global__ void k_scatter(const float* __restrict__ h, int ldh, int ncol,
                          const float* __restrict__ dinv,
                          const int* __restrict__ row, const int* __restrict__ col,
                          float* __restrict__ agg, int lda, int E) {
    int gtid   = blockIdx.x * blockDim.x + threadIdx.x;
    int wave   = gtid >> 6;
    int lane   = threadIdx.x & 63;
    int nwaves = (gridDim.x * blockDim.x) >> 6;
    for (int e = wave; e < E; e += nwaves) {
        int r = row[e];
        int c = col[e];
        float coef = dinv[r] * dinv[c];
        const float* hr = h + (size_t)r * ldh;
        float* ac = agg + (size_t)c * lda;
        for (int j = lane; j < ncol; j += 64)
            atomicAdd(&ac[j], hr[j] * coef);
    }
}

// ---------------- conv1 epilogue: A <- [relu(agg + h*invdeg + b1) | xproj] ----------------
// A holds h (128 cols used, ld 132); B holds agg1. Writes h1cat into A (132 cols).
__global__ void k_combine1(float* __restrict__ A, const float* __restrict__ B,
                           const float* __restrict__ invdeg, const float* __restrict__ b1,
                           const float* __restrict__ xproj, int n) {
    int i = blockIdx.x * blockDim.x + threadIdx.x;
    int stride = gridDim.x * blockDim.x;
    int total = n * H2;
    for (; i < total; i += stride) {
        int node = i / H2;
        int c = i - node * H2;
        float v;
        if (c < H1) {
            v = B[i] + A[i] * invdeg[node] + b1[c];
            v = v > 0.0f ? v : 0.0f;
        } else {
            v = xproj[node * PROJ + (c - H1)];
        }
        A[i] = v;
    }
}

// ---------------- final: out <- [agg2 + h2*invdeg + b2 | xproj] ----------------
__global__ void k_final(const float* __restrict__ agg2, const float* __restrict__ h2,
                        const float* __restrict__ invdeg, const float* __restrict__ b2,
                        const float* __restrict__ xproj, float* __restrict__ out, int n) {
    int i = blockIdx.x * blockDim.x + threadIdx.x;
    int stride = gridDim.x * blockDim.x;
    int total = n * OUTW;
    for (; i < total; i += stride) {
        int node = i / OUTW;
        int c = i - node * OUTW;
        float v;
        if (c < H2) {
            int j = node * H2 + c;
            v = agg2[j] + h2[j] * invdeg[node] + b2[c];
        } else {
            v = xproj[node * PROJ + (c - H2)];
        }
        out[i] = v;
    }
}

extern "C" void kernel_launch(void* const* d_in, const int* in_sizes, int n_in,
                              void* d_out, int out_size, void* d_ws, size_t ws_size,
                              hipStream_t stream) {
    const int*   ei = (const int*)d_in[0];       // [2, E] row-major: row=ei[0:E), col=ei[E:2E)
    const float* x  = (const float*)d_in[1];     // [NN, 128]
    const float* Wp = (const float*)d_in[2];     // [128, 4]
    const float* W1 = (const float*)d_in[3];     // [128, 128]
    const float* b1 = (const float*)d_in[4];     // [128]
    const float* W2 = (const float*)d_in[5];     // [132, 132]
    const float* b2 = (const float*)d_in[6];     // [132]
    float* out = (float*)d_out;

    const int E = in_sizes[0] / 2;
    const int* erow = ei;
    const int* ecol = ei + E;

    // workspace layout (floats)
    float* A      = (float*)d_ws;         // NN*132  : h / h1cat / agg2
    float* B      = A + (size_t)NN * H2;  // NN*132  : agg1 / h2
    float* xproj  = B + (size_t)NN * H2;  // NN*4
    float* dinv   = xproj + (size_t)NN * PROJ; // NN
    float* invdeg = dinv + NN;            // NN  (deg -> invdeg)

    const int T = 256;

    // 1. degree
    k_fill<<<(NN + T - 1) / T, T, 0, stream>>>(invdeg, NN, 1.0f);
    k_count<<<2048, T, 0, stream>>>(ecol, E, invdeg);
    k_dinv<<<(NN + T - 1) / T, T, 0, stream>>>(invdeg, dinv, NN);

    // 2. h = x @ W1 (into A, ld 132); xproj = x @ Wp
    int gblocks = (NN + GROWS - 1) / GROWS;
    size_t lds128 = (size_t)GROWS * 128 * sizeof(float);
    size_t lds132 = (size_t)GROWS * 132 * sizeof(float);
    k_gemm<<<gblocks, T, lds128, stream>>>(x, H1, H1, W1, H1, H1, A, H2, NN);
    k_gemm<<<gblocks, T, lds128, stream>>>(x, H1, H1, Wp, PROJ, PROJ, xproj, PROJ, NN);

    // 3. agg1 = scatter(h) into B
    k_zero<<<4096, T, 0, stream>>>(B, NN * H2);
    k_scatter<<<8192, T, 0, stream>>>(A, H2, H1, dinv, erow, ecol, B, H2, E);

    // 4. h1cat = [relu(agg1 + h*invdeg + b1) | xproj]  (in-place into A)
    k_combine1<<<4096, T, 0, stream>>>(A, B, invdeg, b1, xproj, NN);

    // 5. h2 = h1cat @ W2 (into B)
    k_gemm<<<gblocks, T, lds132, stream>>>(A, H2, H2, W2, H2, H2, B, H2, NN);

    // 6. agg2 = scatter(h2) into A
    k_zero<<<4096, T, 0, stream>>>(A, NN * H2);
    k_scatter<<<8192, T, 0, stream>>>(B, H2, H2, dinv, erow, ecol, A, H2, E);

    // 7. out = [agg2 + h2*invdeg + b2 | xproj]
    k_final<<<4096, T, 0, stream>>>(A, B, invdeg, b2, xproj, out, NN);
}

// Round 2
// 685.490 us; speedup vs baseline: 1.7668x; 1.7668x over previous
//
#include <hip/hip_runtime.h>

#define NN 50000
#define H1 128     // conv1 width
#define H2 132     // conv2 width (128 + 4 proj)
#define PROJ 4
#define OUTW 136   // 132 + 4
#define GROWS 32

// ---------------- CSR build ----------------

__global__ void k_zero_i(int* __restrict__ p, int n) {
    int i = blockIdx.x * blockDim.x + threadIdx.x;
    if (i < n) p[i] = 0;
}

__global__ void k_hist(const int* __restrict__ col, int E, int* __restrict__ cnt) {
    int i = blockIdx.x * blockDim.x + threadIdx.x;
    if (i < E) atomicAdd(&cnt[col[i]], 1);
}

// exclusive scan of cnt[0..n) -> starts[0..n]; also copies starts into cursor
__global__ void k_scan(const int* __restrict__ cnt, int* __restrict__ starts,
                       int* __restrict__ cursor, int n) {
    __shared__ int psum[1024];
    int tid = threadIdx.x;
    int chunk = (n + 1023) / 1024;
    int lo = tid * chunk;
    int hi = lo + chunk; if (hi > n) hi = n;
    int s = 0;
    for (int i = lo; i < hi; ++i) s += cnt[i];
    psum[tid] = s;
    __syncthreads();
    // Hillis-Steele inclusive scan over 1024 partials
    for (int off = 1; off < 1024; off <<= 1) {
        int v = psum[tid];
        int add = (tid >= off) ? psum[tid - off] : 0;
        __syncthreads();
        psum[tid] = v + add;
        __syncthreads();
    }
    int base = psum[tid] - s;  // exclusive base for this thread's chunk
    int run = base;
    for (int i = lo; i < hi; ++i) {
        starts[i] = run;
        cursor[i] = run;
        run += cnt[i];
    }
    if (tid == 1023) starts[n] = psum[1023];
}

__global__ void k_dinv(const int* __restrict__ cnt, float* __restrict__ dinv,
                       float* __restrict__ invdeg, int n) {
    int i = blockIdx.x * blockDim.x + threadIdx.x;
    if (i < n) {
        float d = (float)cnt[i] + 1.0f;  // + self loop
        dinv[i] = rsqrtf(d);
        invdeg[i] = 1.0f / d;
    }
}

__global__ void k_place(const int* __restrict__ row, const int* __restrict__ col, int E,
                        int* __restrict__ cursor, const float* __restrict__ dinv,
                        int* __restrict__ rows_s, float* __restrict__ coef_s) {
    int i = blockIdx.x * blockDim.x + threadIdx.x;
    if (i < E) {
        int c = col[i];
        int r = row[i];
        int pos = atomicAdd(&cursor[c], 1);
        rows_s[pos] = r;
        coef_s[pos] = dinv[r];
    }
}

// ---------------- FP32 GEMM: out[nrows x ncol] = in[nrows x K] @ W[K x ncol] ----------------
// Block = 32 rows staged in LDS; each thread computes 4 consecutive cols (float4 W loads).
__global__ void k_gemm4(const float* __restrict__ in, int ldin, int K,
                        const float* __restrict__ W, int ldw, int ncol,
                        float* __restrict__ out, int ldout, int nrows) {
    extern __shared__ float xs[];  // GROWS * K
    int row0 = blockIdx.x * GROWS;
    int tid = threadIdx.x;

    for (int idx = tid; idx < GROWS * K; idx += blockDim.x) {
        int r = idx / K, k = idx - r * K;
        int gr = row0 + r;
        xs[idx] = (gr < nrows) ? in[(size_t)gr * ldin + k] : 0.0f;
    }
    __syncthreads();

    int nq = ncol >> 2;  // ncol / 4
    for (int idx = tid; idx < GROWS * nq; idx += blockDim.x) {
        int r = idx / nq, q = idx - r * nq;
        int c = q << 2;
        int gr = row0 + r;
        if (gr >= nrows) continue;
        const float* xr = xs + r * K;
        float4 acc = {0.f, 0.f, 0.f, 0.f};
#pragma unroll 8
        for (int k = 0; k < K; ++k) {
            float xv = xr[k];
            float4 wv = *reinterpret_cast<const float4*>(&W[(size_t)k * ldw + c]);
            acc.x = fmaf(xv, wv.x, acc.x);
            acc.y = fmaf(xv, wv.y, acc.y);
            acc.z = fmaf(xv, wv.z, acc.z);
            acc.w = fmaf(xv, wv.w, acc.w);
        }
        *reinterpret_cast<float4*>(&out[(size_t)gr * ldout + c]) = acc;
    }
}

// ---------------- CSR aggregate + fused epilogue ----------------
// One wave per destination node. acc = sum over incoming edges of dinv[row]*h[row].
// out row = [ maybe_relu(acc*dinv[node] + h[node]*invdeg[node] + bias) | xproj[node] ]
template <int NCOL, bool RELU>
__global__ void k_agg(const float* __restrict__ h, int ldh,
                      const int* __restrict__ starts, const int* __restrict__ rows_s,
                      const float* __restrict__ coef_s,
                      const float* __restrict__ dinv, const float* __restrict__ invdeg,
                      const float* __restrict__ bias, const float* __restrict__ xproj,
                      float* __restrict__ outp) {
    constexpr int KCH = (NCOL + 63) / 64;
    int wavesPerBlock = blockDim.x >> 6;
    int node = blockIdx.x * wavesPerBlock + (threadIdx.x >> 6);
    int lane = threadIdx.x & 63;
    if (node >= NN) return;

    int s = starts[node];
    int e = starts[node + 1];

    float acc[KCH];
#pragma unroll
    for (int k = 0; k < KCH; ++k) acc[k] = 0.0f;

    for (int i = s; i < e; ++i) {
        int r = rows_s[i];
        float cf = coef_s[i];
        const float* hr = h + (size_t)r * ldh;
#pragma unroll
        for (int k = 0; k < KCH; ++k) {
            int j = lane + 64 * k;
            if ((NCOL & 63) == 0 || j < NCOL)
                acc[k] = fmaf(cf, hr[j], acc[k]);
        }
    }

    float dc = dinv[node];
    float idg = invdeg[node];
    const float* hself = h + (size_t)node * ldh;
    float* orow = outp + (size_t)node * (NCOL + PROJ);
#pragma unroll
    for (int k = 0; k < KCH; ++k) {
        int j = lane + 64 * k;
        if ((NCOL & 63) == 0 || j < NCOL) {
            float v = acc[k] * dc + hself[j] * idg + bias[j];
            if (RELU) v = fmaxf(v, 0.0f);
            orow[j] = v;
        }
    }
    if (lane < PROJ) orow[NCOL + lane] = xproj[node * PROJ + lane];
}

extern "C" void kernel_launch(void* const* d_in, const int* in_sizes, int n_in,
                              void* d_out, int out_size, void* d_ws, size_t ws_size,
                              hipStream_t stream) {
    const int*   ei = (const int*)d_in[0];       // [2, E]: row = ei[0:E), col = ei[E:2E)
    const float* x  = (const float*)d_in[1];     // [NN, 128]
    const float* Wp = (const float*)d_in[2];     // [128, 4]
    const float* W1 = (const float*)d_in[3];     // [128, 128]
    const float* b1 = (const float*)d_in[4];     // [128]
    const float* W2 = (const float*)d_in[5];     // [132, 132]
    const float* b2 = (const float*)d_in[6];     // [132]
    float* out = (float*)d_out;

    const int E = in_sizes[0] / 2;
    const int* erow = ei;
    const int* ecol = ei + E;

    // workspace layout (4-byte units)
    float* A      = (float*)d_ws;                  // NN*132 : h (ld 128) then h2 (ld 132)
    float* B      = A + (size_t)NN * H2;           // NN*132 : h1cat (ld 132)
    float* xproj  = B + (size_t)NN * H2;           // NN*4
    float* dinv   = xproj + (size_t)NN * PROJ;     // NN
    float* invdeg = dinv + NN;                     // NN
    int*   cnt    = (int*)(invdeg + NN);           // NN
    int*   cursor = cnt + NN;                      // NN
    int*   starts = cursor + NN;                   // NN+1
    int*   rows_s = starts + NN + 1;               // E
    float* coef_s = (float*)(rows_s + E);          // E

    const int T = 256;
    const int eblocks = (E + T - 1) / T;
    const int nblocks = (NN + T - 1) / T;

    // 1. CSR build + degree
    k_zero_i<<<nblocks, T, 0, stream>>>(cnt, NN);
    k_hist<<<eblocks, T, 0, stream>>>(ecol, E, cnt);
    k_scan<<<1, 1024, 0, stream>>>(cnt, starts, cursor, NN);
    k_dinv<<<nblocks, T, 0, stream>>>(cnt, dinv, invdeg, NN);
    k_place<<<eblocks, T, 0, stream>>>(erow, ecol, E, cursor, dinv, rows_s, coef_s);

    // 2. h = x @ W1 (A, ld 128); xproj = x @ Wp
    int gblocks = (NN + GROWS - 1) / GROWS;
    size_t lds128 = (size_t)GROWS * 128 * sizeof(float);
    size_t lds132 = (size_t)GROWS * 132 * sizeof(float);
    k_gemm4<<<gblocks, T, lds128, stream>>>(x, H1, H1, W1, H1, H1, A, H1, NN);
    k_gemm4<<<gblocks, T, lds128, stream>>>(x, H1, H1, Wp, PROJ, PROJ, xproj, PROJ, NN);

    // 3. conv1 aggregate + epilogue -> B = [relu(agg1 + h*invdeg + b1) | xproj], ld 132
    int ablocks = (NN + 3) / 4;  // 4 waves per 256-thread block
    k_agg<H1, true><<<ablocks, T, 0, stream>>>(A, H1, starts, rows_s, coef_s,
                                               dinv, invdeg, b1, xproj, B);

    // 4. h2 = h1cat @ W2 -> A (ld 132)
    k_gemm4<<<gblocks, T, lds132, stream>>>(B, H2, H2, W2, H2, H2, A, H2, NN);

    // 5. conv2 aggregate + epilogue -> out = [agg2 + h2*invdeg + b2 | xproj], ld 136
    k_agg<H2, false><<<ablocks, T, 0, stream>>>(A, H2, starts, rows_s, coef_s,
                                                dinv, invdeg, b2, xproj, out);
}

// Round 3
// 431.028 us; speedup vs baseline: 2.8098x; 1.5904x over previous
//
#include <hip/hip_runtime.h>

#define NN   50000
#define MPAD 50048   // 782 * 64

typedef __attribute__((ext_vector_type(8))) short bf16x8;
typedef __attribute__((ext_vector_type(4))) float f32x4;
typedef unsigned int  u32;
typedef unsigned short u16;

__device__ __forceinline__ u16 f2bf(float f) {
    u32 u = __float_as_uint(f);
    return (u16)((u + 0x7fffu + ((u >> 16) & 1u)) >> 16);
}
__device__ __forceinline__ float bflo(u32 u) { return __uint_as_float(u << 16); }
__device__ __forceinline__ float bfhi(u32 u) { return __uint_as_float(u & 0xffff0000u); }
__device__ __forceinline__ u32 pack2(float x, float y) {
    return (u32)f2bf(x) | ((u32)f2bf(y) << 16);
}

// ---------------- CSR build ----------------

__global__ void k_zero_i(int* __restrict__ p, int n) {
    int i = blockIdx.x * blockDim.x + threadIdx.x;
    if (i < n) p[i] = 0;
}

__global__ void k_hist(const int* __restrict__ col, int E, int* __restrict__ cnt) {
    int i = blockIdx.x * blockDim.x + threadIdx.x;
    if (i < E) atomicAdd(&cnt[col[i]], 1);
}

__global__ void k_scan(const int* __restrict__ cnt, int* __restrict__ starts,
                       int* __restrict__ cursor, int n) {
    __shared__ int psum[1024];
    int tid = threadIdx.x;
    int chunk = (n + 1023) / 1024;
    int lo = tid * chunk;
    int hi = lo + chunk; if (hi > n) hi = n;
    int s = 0;
    for (int i = lo; i < hi; ++i) s += cnt[i];
    psum[tid] = s;
    __syncthreads();
    for (int off = 1; off < 1024; off <<= 1) {
        int v = psum[tid];
        int add = (tid >= off) ? psum[tid - off] : 0;
        __syncthreads();
        psum[tid] = v + add;
        __syncthreads();
    }
    int run = psum[tid] - s;
    for (int i = lo; i < hi; ++i) {
        starts[i] = run;
        cursor[i] = run;
        run += cnt[i];
    }
    if (tid == 1023) starts[n] = psum[1023];
}

__global__ void k_dinv(const int* __restrict__ cnt, float* __restrict__ dinv,
                       float* __restrict__ invdeg, int n) {
    int i = blockIdx.x * blockDim.x + threadIdx.x;
    if (i < n) {
        float d = (float)cnt[i] + 1.0f;
        dinv[i] = rsqrtf(d);
        invdeg[i] = 1.0f / d;
    }
}

__global__ void k_place(const int* __restrict__ row, const int* __restrict__ col, int E,
                        int* __restrict__ cursor, const float* __restrict__ dinv,
                        int* __restrict__ rows_s, float* __restrict__ coef_s) {
    int i = blockIdx.x * blockDim.x + threadIdx.x;
    if (i < E) {
        int c = col[i];
        int r = row[i];
        int pos = atomicAdd(&cursor[c], 1);
        rows_s[pos] = r;
        coef_s[pos] = dinv[r];
    }
}

// ---------------- prep: fp32 -> bf16 conversions ----------------

// x [NN,128] f32 -> xb [MPAD,128] bf16 (pad rows left stale: harmless, never consumed)
__global__ void k_convx(const float* __restrict__ x, u16* __restrict__ xb) {
    int i = blockIdx.x * blockDim.x + threadIdx.x;   // 8 elems per thread
    if (i >= NN * 128 / 8) return;
    const float4* xp = (const float4*)x;
    float4 a = xp[2 * i], b = xp[2 * i + 1];
    uint4 w;
    w.x = pack2(a.x, a.y); w.y = pack2(a.z, a.w);
    w.z = pack2(b.x, b.y); w.w = pack2(b.z, b.w);
    *(uint4*)(xb + (size_t)i * 8) = w;
}

// W1t [144][128] bf16: row n = col n of [W1 | Wp], zero for n>=132
__global__ void k_prep_w1(const float* __restrict__ W1, const float* __restrict__ Wp,
                          u16* __restrict__ Wt) {
    int i = blockIdx.x * blockDim.x + threadIdx.x;
    if (i >= 144 * 128) return;
    int n = i >> 7, k = i & 127;
    float v = 0.f;
    if (n < 128) v = W1[k * 128 + n];
    else if (n < 132) v = Wp[k * 4 + (n - 128)];
    Wt[i] = f2bf(v);
}

// W2t [144][160] bf16: row n = col n of W2 (132x132), zero-padded (handles K-pad too)
__global__ void k_prep_w2(const float* __restrict__ W2, u16* __restrict__ Wt) {
    int i = blockIdx.x * blockDim.x + threadIdx.x;
    if (i >= 144 * 160) return;
    int n = i / 160, k = i - n * 160;
    float v = (n < 132 && k < 132) ? W2[k * 132 + n] : 0.f;
    Wt[i] = f2bf(v);
}

// ---------------- MFMA GEMM: C[MPAD][144] = A[MPAD][K] @ Bt[144][K]^T (all bf16) ----------------
// 1 wave = 16 rows x 144 cols (9 tiles). Operands swapped so each lane holds
// 4 consecutive output cols of one row -> packed 8B stores.
template<int K>
__global__ __launch_bounds__(256) void k_gemm_mfma(const u16* __restrict__ A,
                                                   const u16* __restrict__ Bt,
                                                   u16* __restrict__ C) {
    int lane = threadIdx.x & 63;
    int wv = threadIdx.x >> 6;
    int rbase = blockIdx.x * 64 + wv * 16;
    int lr = lane & 15;
    int kk = (lane >> 4) * 8;

    const u16* ap = A + (size_t)(rbase + lr) * K + kk;
    const u16* bp = Bt + (size_t)lr * K + kk;

    f32x4 acc[9] = {};
#pragma unroll
    for (int ks = 0; ks < K / 32; ++ks) {
        bf16x8 af = *(const bf16x8*)(ap + ks * 32);
#pragma unroll
        for (int t = 0; t < 9; ++t) {
            bf16x8 bf = *(const bf16x8*)(bp + (size_t)(t * 16) * K + ks * 32);
            // swapped: D[n][m] with n=(lane>>4)*4+reg (col tile), m=lane&15 (row)
            acc[t] = __builtin_amdgcn_mfma_f32_16x16x32_bf16(bf, af, acc[t], 0, 0, 0);
        }
    }

    int n0 = (lane >> 4) * 4;
    u16* crow = C + (size_t)(rbase + lr) * 144;
#pragma unroll
    for (int t = 0; t < 9; ++t) {
        ushort4 w;
        w.x = f2bf(acc[t][0]); w.y = f2bf(acc[t][1]);
        w.z = f2bf(acc[t][2]); w.w = f2bf(acc[t][3]);
        *(ushort4*)(crow + 16 * t + n0) = w;
    }
}

// ---------------- aggregates (CSR gather, bf16 rows) ----------------

// conv1: h=[MPAD][144] ([h(128)|xproj(4)|pad]); out = h1cat bf16 [MPAD][160]
__global__ void k_agg1(const u16* __restrict__ h, const int* __restrict__ starts,
                       const int* __restrict__ rows_s, const float* __restrict__ coef_s,
                       const float* __restrict__ dinv, const float* __restrict__ invdeg,
                       const float* __restrict__ b1, u16* __restrict__ outp) {
    int node = blockIdx.x * (blockDim.x >> 6) + (threadIdx.x >> 6);
    int lane = threadIdx.x & 63;
    if (node >= NN) return;
    int s = starts[node], e = starts[node + 1];

    float ax = 0.f, ay = 0.f;
    for (int i = s; i < e; ++i) {
        int r = rows_s[i];
        float cf = coef_s[i];
        u32 u = *(const u32*)(h + (size_t)r * 144 + 2 * lane);
        ax = fmaf(cf, bflo(u), ax);
        ay = fmaf(cf, bfhi(u), ay);
    }
    float dc = dinv[node], idg = invdeg[node];
    u32 us = *(const u32*)(h + (size_t)node * 144 + 2 * lane);
    float2 bv = *(const float2*)(b1 + 2 * lane);
    float vx = fmaxf(fmaf(ax, dc, fmaf(bflo(us), idg, bv.x)), 0.f);
    float vy = fmaxf(fmaf(ay, dc, fmaf(bfhi(us), idg, bv.y)), 0.f);

    u32* orow = (u32*)(outp + (size_t)node * 160);
    orow[lane] = pack2(vx, vy);
    if (lane < 2) {  // copy xproj pairs (cols 128..131)
        orow[64 + lane] = *(const u32*)(h + (size_t)node * 144 + 128 + 2 * lane);
    }
}

// conv2: h2=[MPAD][144] (h2(132)|pad); h1 gives xproj; out fp32 [NN][136]
__global__ void k_agg2(const u16* __restrict__ h2, const u16* __restrict__ h1,
                       const int* __restrict__ starts,
                       const int* __restrict__ rows_s, const float* __restrict__ coef_s,
                       const float* __restrict__ dinv, const float* __restrict__ invdeg,
                       const float* __restrict__ b2, float* __restrict__ outp) {
    int node = blockIdx.x * (blockDim.x >> 6) + (threadIdx.x >> 6);
    int lane = threadIdx.x & 63;
    if (node >= NN) return;
    int s = starts[node], e = starts[node + 1];

    float ax = 0.f, ay = 0.f, cx = 0.f, cy = 0.f;
    for (int i = s; i < e; ++i) {
        int r = rows_s[i];
        float cf = coef_s[i];
        const u32* hr = (const u32*)(h2 + (size_t)r * 144);
        u32 u = hr[lane];
        ax = fmaf(cf, bflo(u), ax);
        ay = fmaf(cf, bfhi(u), ay);
        if (lane < 2) {
            u32 u2 = hr[64 + lane];
            cx = fmaf(cf, bflo(u2), cx);
            cy = fmaf(cf, bfhi(u2), cy);
        }
    }
    float dc = dinv[node], idg = invdeg[node];
    const u32* hs = (const u32*)(h2 + (size_t)node * 144);
    u32 us = hs[lane];
    float2 bv = *(const float2*)(b2 + 2 * lane);
    float vx = fmaf(ax, dc, fmaf(bflo(us), idg, bv.x));
    float vy = fmaf(ay, dc, fmaf(bfhi(us), idg, bv.y));
    float* orow = outp + (size_t)node * 136;
    *(float2*)(orow + 2 * lane) = make_float2(vx, vy);

    if (lane < 2) {
        u32 us2 = hs[64 + lane];
        float2 bb = *(const float2*)(b2 + 128 + 2 * lane);
        float wx = fmaf(cx, dc, fmaf(bflo(us2), idg, bb.x));
        float wy = fmaf(cy, dc, fmaf(bfhi(us2), idg, bb.y));
        *(float2*)(orow + 128 + 2 * lane) = make_float2(wx, wy);
        u32 up = ((const u32*)(h1 + (size_t)node * 144))[64 + lane];
        *(float2*)(orow + 132 + 2 * lane) = make_float2(bflo(up), bfhi(up));
    }
}

extern "C" void kernel_launch(void* const* d_in, const int* in_sizes, int n_in,
                              void* d_out, int out_size, void* d_ws, size_t ws_size,
                              hipStream_t stream) {
    const int*   ei = (const int*)d_in[0];
    const float* x  = (const float*)d_in[1];
    const float* Wp = (const float*)d_in[2];
    const float* W1 = (const float*)d_in[3];
    const float* b1 = (const float*)d_in[4];
    const float* W2 = (const float*)d_in[5];
    const float* b2 = (const float*)d_in[6];
    float* out = (float*)d_out;

    const int E = in_sizes[0] / 2;
    const int* erow = ei;
    const int* ecol = ei + E;

    // workspace layout
    char* p = (char*)d_ws;
    u16* HcX  = (u16*)p; p += (size_t)MPAD * 144 * 2;  // xb [MPAD][128] then h2 [MPAD][144]
    u16* Hc1  = (u16*)p; p += (size_t)MPAD * 144 * 2;  // conv1 out [h|xproj|pad]
    u16* Hcat = (u16*)p; p += (size_t)MPAD * 160 * 2;  // h1cat bf16, K padded to 160
    u16* W1t  = (u16*)p; p += 144 * 128 * 2;
    u16* W2t  = (u16*)p; p += 144 * 160 * 2;
    float* dinv   = (float*)p; p += NN * 4;
    float* invdeg = (float*)p; p += NN * 4;
    int* cnt    = (int*)p; p += NN * 4;
    int* cursor = (int*)p; p += NN * 4;
    int* starts = (int*)p; p += (size_t)(NN + 1) * 4;
    int* rows_s = (int*)p; p += (size_t)E * 4;
    float* coef_s = (float*)p;

    u16* xb = HcX;
    u16* Hc2 = HcX;

    const int T = 256;
    const int eblocks = (E + T - 1) / T;
    const int nblocks = (NN + T - 1) / T;

    // prep
    k_convx<<<NN * 128 / 8 / T, T, 0, stream>>>(x, xb);
    k_prep_w1<<<(144 * 128 + T - 1) / T, T, 0, stream>>>(W1, Wp, W1t);
    k_prep_w2<<<(144 * 160 + T - 1) / T, T, 0, stream>>>(W2, W2t);

    // CSR
    k_zero_i<<<nblocks, T, 0, stream>>>(cnt, NN);
    k_hist<<<eblocks, T, 0, stream>>>(ecol, E, cnt);
    k_scan<<<1, 1024, 0, stream>>>(cnt, starts, cursor, NN);
    k_dinv<<<nblocks, T, 0, stream>>>(cnt, dinv, invdeg, NN);
    k_place<<<eblocks, T, 0, stream>>>(erow, ecol, E, cursor, dinv, rows_s, coef_s);

    const int gblocks = MPAD / 64;       // 782
    const int ablocks = (NN + 3) / 4;    // 4 waves / block

    // conv1
    k_gemm_mfma<128><<<gblocks, T, 0, stream>>>(xb, W1t, Hc1);
    k_agg1<<<ablocks, T, 0, stream>>>(Hc1, starts, rows_s, coef_s, dinv, invdeg, b1, Hcat);

    // conv2
    k_gemm_mfma<160><<<gblocks, T, 0, stream>>>(Hcat, W2t, Hc2);
    k_agg2<<<ablocks, T, 0, stream>>>(Hc2, Hc1, starts, rows_s, coef_s, dinv, invdeg, b2, out);
}

// Round 4
// 331.444 us; speedup vs baseline: 3.6541x; 1.3005x over previous
//
#include <hip/hip_runtime.h>

#define NN   50000
#define MPAD 50048   // 782 * 64

#define SCAN_C 4
#define SCAN_T 256
#define SCAN_B 49    // ceil(NN / (SCAN_C*SCAN_T))

typedef __attribute__((ext_vector_type(8))) short bf16x8;
typedef __attribute__((ext_vector_type(4))) float f32x4;
typedef unsigned int  u32;
typedef unsigned short u16;

__device__ __forceinline__ u16 f2bf(float f) {
    u32 u = __float_as_uint(f);
    return (u16)((u + 0x7fffu + ((u >> 16) & 1u)) >> 16);
}
__device__ __forceinline__ float bflo(u32 u) { return __uint_as_float(u << 16); }
__device__ __forceinline__ float bfhi(u32 u) { return __uint_as_float(u & 0xffff0000u); }
__device__ __forceinline__ u32 pack2(float x, float y) {
    return (u32)f2bf(x) | ((u32)f2bf(y) << 16);
}

// ---------------- CSR build ----------------

__global__ void k_zero_i(int* __restrict__ p, int n) {
    int i = blockIdx.x * blockDim.x + threadIdx.x;
    if (i < n) p[i] = 0;
}

__global__ void k_hist(const int* __restrict__ col, int E, int* __restrict__ cnt) {
    int i = blockIdx.x * blockDim.x + threadIdx.x;
    if (i < E) atomicAdd(&cnt[col[i]], 1);
}

// phase A: per-thread sums (4 elems each) + per-block sums
__global__ void k_scanA(const int* __restrict__ cnt, int* __restrict__ tsum,
                        int* __restrict__ bsum) {
    int tid = threadIdx.x, b = blockIdx.x;
    int t = b * SCAN_T + tid;
    int i0 = t * SCAN_C;
    int s = 0;
#pragma unroll
    for (int j = 0; j < SCAN_C; ++j) {
        int i = i0 + j;
        if (i < NN) s += cnt[i];
    }
    tsum[t] = s;
    __shared__ int red[SCAN_T];
    red[tid] = s;
    __syncthreads();
    for (int off = SCAN_T / 2; off > 0; off >>= 1) {
        if (tid < off) red[tid] += red[tid + off];
        __syncthreads();
    }
    if (tid == 0) bsum[b] = red[0];
}

// phase B: one wave scans the 49 block sums; lane SCAN_B writes the grand total
__global__ void k_scanB(const int* __restrict__ bsum, int* __restrict__ bbase,
                        int* __restrict__ starts) {
    int lane = threadIdx.x;
    int v = (lane < SCAN_B) ? bsum[lane] : 0;
    int inc = v;
    for (int off = 1; off < 64; off <<= 1) {
        int o = __shfl_up(inc, off, 64);
        if (lane >= off) inc += o;
    }
    int exc = inc - v;
    if (lane < SCAN_B) bbase[lane] = exc;
    if (lane == SCAN_B) starts[NN] = exc;  // sum of all blocks
}

// phase C: block-local scan + base -> starts/cursor; fused degree math
__global__ void k_scanC(const int* __restrict__ cnt, const int* __restrict__ tsum,
                        const int* __restrict__ bbase, int* __restrict__ starts,
                        int* __restrict__ cursor, float* __restrict__ dinv,
                        float* __restrict__ invdeg) {
    int tid = threadIdx.x, b = blockIdx.x;
    __shared__ int sc[SCAN_T];
    int t = b * SCAN_T + tid;
    int s = tsum[t];
    sc[tid] = s;
    __syncthreads();
    for (int off = 1; off < SCAN_T; off <<= 1) {
        int add = (tid >= off) ? sc[tid - off] : 0;
        __syncthreads();
        sc[tid] += add;
        __syncthreads();
    }
    int run = bbase[b] + sc[tid] - s;
    int i0 = t * SCAN_C;
#pragma unroll
    for (int j = 0; j < SCAN_C; ++j) {
        int i = i0 + j;
        if (i < NN) {
            int c = cnt[i];
            starts[i] = run;
            cursor[i] = run;
            run += c;
            float d = (float)c + 1.0f;
            dinv[i] = rsqrtf(d);
            invdeg[i] = 1.0f / d;
        }
    }
}

__global__ void k_place(const int* __restrict__ row, const int* __restrict__ col, int E,
                        int* __restrict__ cursor, const float* __restrict__ dinv,
                        int* __restrict__ rows_s, float* __restrict__ coef_s) {
    int i = blockIdx.x * blockDim.x + threadIdx.x;
    if (i < E) {
        int c = col[i];
        int r = row[i];
        int pos = atomicAdd(&cursor[c], 1);
        rows_s[pos] = r;
        coef_s[pos] = dinv[r];
    }
}

// ---------------- prep: fp32 -> bf16 conversions ----------------

__global__ void k_convx(const float* __restrict__ x, u16* __restrict__ xb) {
    int i = blockIdx.x * blockDim.x + threadIdx.x;   // 8 elems per thread
    if (i >= NN * 128 / 8) return;
    const float4* xp = (const float4*)x;
    float4 a = xp[2 * i], b = xp[2 * i + 1];
    uint4 w;
    w.x = pack2(a.x, a.y); w.y = pack2(a.z, a.w);
    w.z = pack2(b.x, b.y); w.w = pack2(b.z, b.w);
    *(uint4*)(xb + (size_t)i * 8) = w;
}

// W1t [144][128] bf16: row n = col n of [W1 | Wp], zero for n>=132
__global__ void k_prep_w1(const float* __restrict__ W1, const float* __restrict__ Wp,
                          u16* __restrict__ Wt) {
    int i = blockIdx.x * blockDim.x + threadIdx.x;
    if (i >= 144 * 128) return;
    int n = i >> 7, k = i & 127;
    float v = 0.f;
    if (n < 128) v = W1[k * 128 + n];
    else if (n < 132) v = Wp[k * 4 + (n - 128)];
    Wt[i] = f2bf(v);
}

// W2t [144][160] bf16: row n = col n of W2 (132x132), zero-padded
__global__ void k_prep_w2(const float* __restrict__ W2, u16* __restrict__ Wt) {
    int i = blockIdx.x * blockDim.x + threadIdx.x;
    if (i >= 144 * 160) return;
    int n = i / 160, k = i - n * 160;
    float v = (n < 132 && k < 132) ? W2[k * 132 + n] : 0.f;
    Wt[i] = f2bf(v);
}

// ---------------- MFMA GEMM: C[MPAD][144] = A[MPAD][K] @ Bt[144][K]^T (bf16) ----------------
template<int K>
__global__ __launch_bounds__(256) void k_gemm_mfma(const u16* __restrict__ A,
                                                   const u16* __restrict__ Bt,
                                                   u16* __restrict__ C) {
    int lane = threadIdx.x & 63;
    int wv = threadIdx.x >> 6;
    int rbase = blockIdx.x * 64 + wv * 16;
    int lr = lane & 15;
    int kk = (lane >> 4) * 8;

    const u16* ap = A + (size_t)(rbase + lr) * K + kk;
    const u16* bp = Bt + (size_t)lr * K + kk;

    f32x4 acc[9] = {};
#pragma unroll
    for (int ks = 0; ks < K / 32; ++ks) {
        bf16x8 af = *(const bf16x8*)(ap + ks * 32);
#pragma unroll
        for (int t = 0; t < 9; ++t) {
            bf16x8 bf = *(const bf16x8*)(bp + (size_t)(t * 16) * K + ks * 32);
            acc[t] = __builtin_amdgcn_mfma_f32_16x16x32_bf16(bf, af, acc[t], 0, 0, 0);
        }
    }

    int n0 = (lane >> 4) * 4;
    u16* crow = C + (size_t)(rbase + lr) * 144;
#pragma unroll
    for (int t = 0; t < 9; ++t) {
        ushort4 w;
        w.x = f2bf(acc[t][0]); w.y = f2bf(acc[t][1]);
        w.z = f2bf(acc[t][2]); w.w = f2bf(acc[t][3]);
        *(ushort4*)(crow + 16 * t + n0) = w;
    }
}

// ---------------- aggregates (CSR gather, bf16 rows) ----------------

__global__ void k_agg1(const u16* __restrict__ h, const int* __restrict__ starts,
                       const int* __restrict__ rows_s, const float* __restrict__ coef_s,
                       const float* __restrict__ dinv, const float* __restrict__ invdeg,
                       const float* __restrict__ b1, u16* __restrict__ outp) {
    int node = blockIdx.x * (blockDim.x >> 6) + (threadIdx.x >> 6);
    int lane = threadIdx.x & 63;
    if (node >= NN) return;
    int s = starts[node], e = starts[node + 1];

    float ax = 0.f, ay = 0.f;
    for (int i = s; i < e; ++i) {
        int r = rows_s[i];
        float cf = coef_s[i];
        u32 u = *(const u32*)(h + (size_t)r * 144 + 2 * lane);
        ax = fmaf(cf, bflo(u), ax);
        ay = fmaf(cf, bfhi(u), ay);
    }
    float dc = dinv[node], idg = invdeg[node];
    u32 us = *(const u32*)(h + (size_t)node * 144 + 2 * lane);
    float2 bv = *(const float2*)(b1 + 2 * lane);
    float vx = fmaxf(fmaf(ax, dc, fmaf(bflo(us), idg, bv.x)), 0.f);
    float vy = fmaxf(fmaf(ay, dc, fmaf(bfhi(us), idg, bv.y)), 0.f);

    u32* orow = (u32*)(outp + (size_t)node * 160);
    orow[lane] = pack2(vx, vy);
    if (lane < 2) {
        orow[64 + lane] = *(const u32*)(h + (size_t)node * 144 + 128 + 2 * lane);
    }
}

__global__ void k_agg2(const u16* __restrict__ h2, const u16* __restrict__ h1,
                       const int* __restrict__ starts,
                       const int* __restrict__ rows_s, const float* __restrict__ coef_s,
                       const float* __restrict__ dinv, const float* __restrict__ invdeg,
                       const float* __restrict__ b2, float* __restrict__ outp) {
    int node = blockIdx.x * (blockDim.x >> 6) + (threadIdx.x >> 6);
    int lane = threadIdx.x & 63;
    if (node >= NN) return;
    int s = starts[node], e = starts[node + 1];

    float ax = 0.f, ay = 0.f, cx = 0.f, cy = 0.f;
    for (int i = s; i < e; ++i) {
        int r = rows_s[i];
        float cf = coef_s[i];
        const u32* hr = (const u32*)(h2 + (size_t)r * 144);
        u32 u = hr[lane];
        ax = fmaf(cf, bflo(u), ax);
        ay = fmaf(cf, bfhi(u), ay);
        if (lane < 2) {
            u32 u2 = hr[64 + lane];
            cx = fmaf(cf, bflo(u2), cx);
            cy = fmaf(cf, bfhi(u2), cy);
        }
    }
    float dc = dinv[node], idg = invdeg[node];
    const u32* hs = (const u32*)(h2 + (size_t)node * 144);
    u32 us = hs[lane];
    float2 bv = *(const float2*)(b2 + 2 * lane);
    float vx = fmaf(ax, dc, fmaf(bflo(us), idg, bv.x));
    float vy = fmaf(ay, dc, fmaf(bfhi(us), idg, bv.y));
    float* orow = outp + (size_t)node * 136;
    *(float2*)(orow + 2 * lane) = make_float2(vx, vy);

    if (lane < 2) {
        u32 us2 = hs[64 + lane];
        float2 bb = *(const float2*)(b2 + 128 + 2 * lane);
        float wx = fmaf(cx, dc, fmaf(bflo(us2), idg, bb.x));
        float wy = fmaf(cy, dc, fmaf(bfhi(us2), idg, bb.y));
        *(float2*)(orow + 128 + 2 * lane) = make_float2(wx, wy);
        u32 up = ((const u32*)(h1 + (size_t)node * 144))[64 + lane];
        *(float2*)(orow + 132 + 2 * lane) = make_float2(bflo(up), bfhi(up));
    }
}

extern "C" void kernel_launch(void* const* d_in, const int* in_sizes, int n_in,
                              void* d_out, int out_size, void* d_ws, size_t ws_size,
                              hipStream_t stream) {
    const int*   ei = (const int*)d_in[0];
    const float* x  = (const float*)d_in[1];
    const float* Wp = (const float*)d_in[2];
    const float* W1 = (const float*)d_in[3];
    const float* b1 = (const float*)d_in[4];
    const float* W2 = (const float*)d_in[5];
    const float* b2 = (const float*)d_in[6];
    float* out = (float*)d_out;

    const int E = in_sizes[0] / 2;
    const int* erow = ei;
    const int* ecol = ei + E;

    // workspace layout
    char* p = (char*)d_ws;
    u16* HcX  = (u16*)p; p += (size_t)MPAD * 144 * 2;  // xb [MPAD][128] then h2 [MPAD][144]
    u16* Hc1  = (u16*)p; p += (size_t)MPAD * 144 * 2;  // conv1 out [h|xproj|pad]
    u16* Hcat = (u16*)p; p += (size_t)MPAD * 160 * 2;  // h1cat bf16, K padded to 160
    u16* W1t  = (u16*)p; p += 144 * 128 * 2;
    u16* W2t  = (u16*)p; p += 144 * 160 * 2;
    float* dinv   = (float*)p; p += NN * 4;
    float* invdeg = (float*)p; p += NN * 4;
    int* cnt    = (int*)p; p += NN * 4;
    int* cursor = (int*)p; p += NN * 4;
    int* starts = (int*)p; p += (size_t)(NN + 1) * 4;
    int* tsum   = (int*)p; p += (size_t)SCAN_B * SCAN_T * 4;
    int* bsum   = (int*)p; p += SCAN_B * 4;
    int* bbase  = (int*)p; p += SCAN_B * 4;
    int* rows_s = (int*)p; p += (size_t)E * 4;
    float* coef_s = (float*)p;

    u16* xb = HcX;
    u16* Hc2 = HcX;

    const int T = 256;
    const int eblocks = (E + T - 1) / T;
    const int nblocks = (NN + T - 1) / T;

    // prep
    k_convx<<<NN * 128 / 8 / T, T, 0, stream>>>(x, xb);
    k_prep_w1<<<(144 * 128 + T - 1) / T, T, 0, stream>>>(W1, Wp, W1t);
    k_prep_w2<<<(144 * 160 + T - 1) / T, T, 0, stream>>>(W2, W2t);

    // CSR build
    k_zero_i<<<nblocks, T, 0, stream>>>(cnt, NN);
    k_hist<<<eblocks, T, 0, stream>>>(ecol, E, cnt);
    k_scanA<<<SCAN_B, SCAN_T, 0, stream>>>(cnt, tsum, bsum);
    k_scanB<<<1, 64, 0, stream>>>(bsum, bbase, starts);
    k_scanC<<<SCAN_B, SCAN_T, 0, stream>>>(cnt, tsum, bbase, starts, cursor, dinv, invdeg);
    k_place<<<eblocks, T, 0, stream>>>(erow, ecol, E, cursor, dinv, rows_s, coef_s);

    const int gblocks = MPAD / 64;       // 782
    const int ablocks = (NN + 3) / 4;    // 4 waves / block

    // conv1
    k_gemm_mfma<128><<<gblocks, T, 0, stream>>>(xb, W1t, Hc1);
    k_agg1<<<ablocks, T, 0, stream>>>(Hc1, starts, rows_s, coef_s, dinv, invdeg, b1, Hcat);

    // conv2
    k_gemm_mfma<160><<<gblocks, T, 0, stream>>>(Hcat, W2t, Hc2);
    k_agg2<<<ablocks, T, 0, stream>>>(Hc2, Hc1, starts, rows_s, coef_s, dinv, invdeg, b2, out);
}

// Round 5
// 232.502 us; speedup vs baseline: 5.2091x; 1.4256x over previous
//
#include <hip/hip_runtime.h>

#define NN   50000
#define MPAD 50048   // 782 * 64

#define SCAN_C 4
#define SCAN_T 256
#define SCAN_B 49    // ceil(NN / (SCAN_C*SCAN_T))

typedef __attribute__((ext_vector_type(8))) short bf16x8;
typedef __attribute__((ext_vector_type(4))) float f32x4;
typedef unsigned int  u32;
typedef unsigned short u16;
typedef unsigned long long u64;

__device__ __forceinline__ u16 f2bf(float f) {
    u32 u = __float_as_uint(f);
    return (u16)((u + 0x7fffu + ((u >> 16) & 1u)) >> 16);
}
__device__ __forceinline__ float bflo(u32 u) { return __uint_as_float(u << 16); }
__device__ __forceinline__ float bfhi(u32 u) { return __uint_as_float(u & 0xffff0000u); }
__device__ __forceinline__ u32 pack2(float x, float y) {
    return (u32)f2bf(x) | ((u32)f2bf(y) << 16);
}

// ---------------- CSR build ----------------

__global__ void k_zero_i(int* __restrict__ p, int n) {
    int i = blockIdx.x * blockDim.x + threadIdx.x;
    if (i < n) p[i] = 0;
}

__global__ void k_hist(const int* __restrict__ col, int E, int* __restrict__ cnt) {
    int i = blockIdx.x * blockDim.x + threadIdx.x;
    if (i < E) atomicAdd(&cnt[col[i]], 1);
}

__global__ void k_scanA(const int* __restrict__ cnt, int* __restrict__ tsum,
                        int* __restrict__ bsum) {
    int tid = threadIdx.x, b = blockIdx.x;
    int t = b * SCAN_T + tid;
    int i0 = t * SCAN_C;
    int s = 0;
#pragma unroll
    for (int j = 0; j < SCAN_C; ++j) {
        int i = i0 + j;
        if (i < NN) s += cnt[i];
    }
    tsum[t] = s;
    __shared__ int red[SCAN_T];
    red[tid] = s;
    __syncthreads();
    for (int off = SCAN_T / 2; off > 0; off >>= 1) {
        if (tid < off) red[tid] += red[tid + off];
        __syncthreads();
    }
    if (tid == 0) bsum[b] = red[0];
}

__global__ void k_scanB(const int* __restrict__ bsum, int* __restrict__ bbase,
                        int* __restrict__ starts) {
    int lane = threadIdx.x;
    int v = (lane < SCAN_B) ? bsum[lane] : 0;
    int inc = v;
    for (int off = 1; off < 64; off <<= 1) {
        int o = __shfl_up(inc, off, 64);
        if (lane >= off) inc += o;
    }
    int exc = inc - v;
    if (lane < SCAN_B) bbase[lane] = exc;
    if (lane == SCAN_B) starts[NN] = exc;
}

__global__ void k_scanC(const int* __restrict__ cnt, const int* __restrict__ tsum,
                        const int* __restrict__ bbase, int* __restrict__ starts,
                        int* __restrict__ cursor, float* __restrict__ dinv,
                        float* __restrict__ invdeg) {
    int tid = threadIdx.x, b = blockIdx.x;
    __shared__ int sc[SCAN_T];
    int t = b * SCAN_T + tid;
    int s = tsum[t];
    sc[tid] = s;
    __syncthreads();
    for (int off = 1; off < SCAN_T; off <<= 1) {
        int add = (tid >= off) ? sc[tid - off] : 0;
        __syncthreads();
        sc[tid] += add;
        __syncthreads();
    }
    int run = bbase[b] + sc[tid] - s;
    int i0 = t * SCAN_C;
#pragma unroll
    for (int j = 0; j < SCAN_C; ++j) {
        int i = i0 + j;
        if (i < NN) {
            int c = cnt[i];
            starts[i] = run;
            cursor[i] = run;
            run += c;
            float d = (float)c + 1.0f;
            dinv[i] = rsqrtf(d);
            invdeg[i] = 1.0f / d;
        }
    }
}

// packed edge record: low32 = source row, high32 = dinv[row] bits
__global__ void k_place(const int* __restrict__ row, const int* __restrict__ col, int E,
                        int* __restrict__ cursor, const float* __restrict__ dinv,
                        u64* __restrict__ ec) {
    int i = blockIdx.x * blockDim.x + threadIdx.x;
    if (i < E) {
        int c = col[i];
        int r = row[i];
        int pos = atomicAdd(&cursor[c], 1);
        ec[pos] = (u64)(u32)r | ((u64)__float_as_uint(dinv[r]) << 32);
    }
}

// ---------------- weight prep ----------------

// W1t [144][128] bf16: row n = col n of [W1 | Wp], zero for n>=132
__global__ void k_prep_w1(const float* __restrict__ W1, const float* __restrict__ Wp,
                          u16* __restrict__ Wt) {
    int i = blockIdx.x * blockDim.x + threadIdx.x;
    if (i >= 144 * 128) return;
    int n = i >> 7, k = i & 127;
    float v = 0.f;
    if (n < 128) v = W1[k * 128 + n];
    else if (n < 132) v = Wp[k * 4 + (n - 128)];
    Wt[i] = f2bf(v);
}

// W2t [144][160] bf16: row n = col n of W2 (132x132), zero-padded (K-pad too)
__global__ void k_prep_w2(const float* __restrict__ W2, u16* __restrict__ Wt) {
    int i = blockIdx.x * blockDim.x + threadIdx.x;
    if (i >= 144 * 160) return;
    int n = i / 160, k = i - n * 160;
    float v = (n < 132 && k < 132) ? W2[k * 132 + n] : 0.f;
    Wt[i] = f2bf(v);
}

// ---------------- MFMA GEMM ----------------
// C[MPAD][144] = A[MPAD][K] @ Bt[144][K]^T.  Cols 0-127 -> Cmain (ld 128),
// cols 128-131 -> Cext (ld 4). A is f32 (CONVF32, ld=K, NN rows) or bf16 (ld=K).
template<int K, bool CONVF32>
__global__ __launch_bounds__(256) void k_gemm_mfma(const void* __restrict__ Ain,
                                                   const u16* __restrict__ Bt,
                                                   u16* __restrict__ Cmain,
                                                   u16* __restrict__ Cext) {
    int lane = threadIdx.x & 63;
    int wv = threadIdx.x >> 6;
    int rbase = blockIdx.x * 64 + wv * 16;
    int lr = lane & 15;
    int kk = (lane >> 4) * 8;
    int arow = rbase + lr;
    if (CONVF32 && arow >= NN) arow = NN - 1;  // x has exactly NN rows

    const u16* bp = Bt + (size_t)lr * K + kk;

    f32x4 acc[9] = {};
#pragma unroll
    for (int ks = 0; ks < K / 32; ++ks) {
        bf16x8 af;
        if (CONVF32) {
            const float* ap = (const float*)Ain + (size_t)arow * K + kk + ks * 32;
            float4 f0 = *(const float4*)ap;
            float4 f1 = *(const float4*)(ap + 4);
            union { uint4 u; bf16x8 v; } cv;
            cv.u.x = pack2(f0.x, f0.y); cv.u.y = pack2(f0.z, f0.w);
            cv.u.z = pack2(f1.x, f1.y); cv.u.w = pack2(f1.z, f1.w);
            af = cv.v;
        } else {
            af = *(const bf16x8*)((const u16*)Ain + (size_t)arow * K + kk + ks * 32);
        }
#pragma unroll
        for (int t = 0; t < 9; ++t) {
            bf16x8 bf = *(const bf16x8*)(bp + (size_t)(t * 16) * K + ks * 32);
            acc[t] = __builtin_amdgcn_mfma_f32_16x16x32_bf16(bf, af, acc[t], 0, 0, 0);
        }
    }

    int n0 = (lane >> 4) * 4;
    int crow = rbase + lr;
    u16* cm = Cmain + (size_t)crow * 128;
#pragma unroll
    for (int t = 0; t < 8; ++t) {
        ushort4 w;
        w.x = f2bf(acc[t][0]); w.y = f2bf(acc[t][1]);
        w.z = f2bf(acc[t][2]); w.w = f2bf(acc[t][3]);
        *(ushort4*)(cm + 16 * t + n0) = w;
    }
    if (n0 == 0) {  // cols 128-131
        ushort4 w;
        w.x = f2bf(acc[8][0]); w.y = f2bf(acc[8][1]);
        w.z = f2bf(acc[8][2]); w.w = f2bf(acc[8][3]);
        *(ushort4*)(Cext + (size_t)crow * 4) = w;
    }
}

// ---------------- aggregates (CSR gather, 256B-aligned bf16 rows) ----------------

// conv1: main=[MPAD][128] h, Xp=[MPAD][4] xproj. out = h1cat bf16 [MPAD][160].
__global__ void k_agg1(const u16* __restrict__ Hm, const u16* __restrict__ Xp,
                       const int* __restrict__ starts, const uint2* __restrict__ ec,
                       const float* __restrict__ dinv, const float* __restrict__ invdeg,
                       const float* __restrict__ b1, u16* __restrict__ outp) {
    int node = blockIdx.x * (blockDim.x >> 6) + (threadIdx.x >> 6);
    int lane = threadIdx.x & 63;
    if (node >= NN) return;
    int s = starts[node], e = starts[node + 1];

    float ax = 0.f, ay = 0.f;
    int i = s;
    for (; i + 4 <= e; i += 4) {
        uint4 q0 = *(const uint4*)(ec + i);
        uint4 q1 = *(const uint4*)(ec + i + 2);
        u32 u0 = *(const u32*)(Hm + ((size_t)q0.x << 7) + 2 * lane);
        u32 u1 = *(const u32*)(Hm + ((size_t)q0.z << 7) + 2 * lane);
        u32 u2 = *(const u32*)(Hm + ((size_t)q1.x << 7) + 2 * lane);
        u32 u3 = *(const u32*)(Hm + ((size_t)q1.z << 7) + 2 * lane);
        float c0 = __uint_as_float(q0.y), c1 = __uint_as_float(q0.w);
        float c2 = __uint_as_float(q1.y), c3 = __uint_as_float(q1.w);
        ax = fmaf(c0, bflo(u0), ax); ay = fmaf(c0, bfhi(u0), ay);
        ax = fmaf(c1, bflo(u1), ax); ay = fmaf(c1, bfhi(u1), ay);
        ax = fmaf(c2, bflo(u2), ax); ay = fmaf(c2, bfhi(u2), ay);
        ax = fmaf(c3, bflo(u3), ax); ay = fmaf(c3, bfhi(u3), ay);
    }
    for (; i < e; ++i) {
        uint2 q = ec[i];
        u32 u = *(const u32*)(Hm + ((size_t)q.x << 7) + 2 * lane);
        float c = __uint_as_float(q.y);
        ax = fmaf(c, bflo(u), ax); ay = fmaf(c, bfhi(u), ay);
    }

    float dc = dinv[node], idg = invdeg[node];
    u32 us = *(const u32*)(Hm + ((size_t)node << 7) + 2 * lane);
    float2 bv = *(const float2*)(b1 + 2 * lane);
    float vx = fmaxf(fmaf(ax, dc, fmaf(bflo(us), idg, bv.x)), 0.f);
    float vy = fmaxf(fmaf(ay, dc, fmaf(bfhi(us), idg, bv.y)), 0.f);

    u32* orow = (u32*)(outp + (size_t)node * 160);
    orow[lane] = pack2(vx, vy);
    if (lane < 2) orow[64 + lane] = *(const u32*)(Xp + (size_t)node * 4 + 2 * lane);
}

// conv2: main=[MPAD][128], ext=[MPAD][4] (cols 128-131); Xp1 = conv1 xproj. out fp32 [NN][136].
__global__ void k_agg2(const u16* __restrict__ Hm, const u16* __restrict__ He,
                       const u16* __restrict__ Xp1,
                       const int* __restrict__ starts, const uint2* __restrict__ ec,
                       const float* __restrict__ dinv, const float* __restrict__ invdeg,
                       const float* __restrict__ b2, float* __restrict__ outp) {
    int node = blockIdx.x * (blockDim.x >> 6) + (threadIdx.x >> 6);
    int lane = threadIdx.x & 63;
    if (node >= NN) return;
    int s = starts[node], e = starts[node + 1];

    float ax = 0.f, ay = 0.f, cx = 0.f, cy = 0.f;
    int i = s;
    for (; i + 4 <= e; i += 4) {
        uint4 q0 = *(const uint4*)(ec + i);
        uint4 q1 = *(const uint4*)(ec + i + 2);
        u32 u0 = *(const u32*)(Hm + ((size_t)q0.x << 7) + 2 * lane);
        u32 u1 = *(const u32*)(Hm + ((size_t)q0.z << 7) + 2 * lane);
        u32 u2 = *(const u32*)(Hm + ((size_t)q1.x << 7) + 2 * lane);
        u32 u3 = *(const u32*)(Hm + ((size_t)q1.z << 7) + 2 * lane);
        float c0 = __uint_as_float(q0.y), c1 = __uint_as_float(q0.w);
        float c2 = __uint_as_float(q1.y), c3 = __uint_as_float(q1.w);
        ax = fmaf(c0, bflo(u0), ax); ay = fmaf(c0, bfhi(u0), ay);
        ax = fmaf(c1, bflo(u1), ax); ay = fmaf(c1, bfhi(u1), ay);
        ax = fmaf(c2, bflo(u2), ax); ay = fmaf(c2, bfhi(u2), ay);
        ax = fmaf(c3, bflo(u3), ax); ay = fmaf(c3, bfhi(u3), ay);
        if (lane < 2) {
            u32 e0 = *(const u32*)(He + ((size_t)q0.x << 2) + 2 * lane);
            u32 e1 = *(const u32*)(He + ((size_t)q0.z << 2) + 2 * lane);
            u32 e2 = *(const u32*)(He + ((size_t)q1.x << 2) + 2 * lane);
            u32 e3 = *(const u32*)(He + ((size_t)q1.z << 2) + 2 * lane);
            cx = fmaf(c0, bflo(e0), cx); cy = fmaf(c0, bfhi(e0), cy);
            cx = fmaf(c1, bflo(e1), cx); cy = fmaf(c1, bfhi(e1), cy);
            cx = fmaf(c2, bflo(e2), cx); cy = fmaf(c2, bfhi(e2), cy);
            cx = fmaf(c3, bflo(e3), cx); cy = fmaf(c3, bfhi(e3), cy);
        }
    }
    for (; i < e; ++i) {
        uint2 q = ec[i];
        u32 u = *(const u32*)(Hm + ((size_t)q.x << 7) + 2 * lane);
        float c = __uint_as_float(q.y);
        ax = fmaf(c, bflo(u), ax); ay = fmaf(c, bfhi(u), ay);
        if (lane < 2) {
            u32 e0 = *(const u32*)(He + ((size_t)q.x << 2) + 2 * lane);
            cx = fmaf(c, bflo(e0), cx); cy = fmaf(c, bfhi(e0), cy);
        }
    }

    float dc = dinv[node], idg = invdeg[node];
    u32 us = *(const u32*)(Hm + ((size_t)node << 7) + 2 * lane);
    float2 bv = *(const float2*)(b2 + 2 * lane);
    float vx = fmaf(ax, dc, fmaf(bflo(us), idg, bv.x));
    float vy = fmaf(ay, dc, fmaf(bfhi(us), idg, bv.y));
    float* orow = outp + (size_t)node * 136;
    *(float2*)(orow + 2 * lane) = make_float2(vx, vy);

    if (lane < 2) {
        u32 us2 = *(const u32*)(He + ((size_t)node << 2) + 2 * lane);
        float2 bb = *(const float2*)(b2 + 128 + 2 * lane);
        float wx = fmaf(cx, dc, fmaf(bflo(us2), idg, bb.x));
        float wy = fmaf(cy, dc, fmaf(bfhi(us2), idg, bb.y));
        *(float2*)(orow + 128 + 2 * lane) = make_float2(wx, wy);
        u32 up = *(const u32*)(Xp1 + ((size_t)node << 2) + 2 * lane);
        *(float2*)(orow + 132 + 2 * lane) = make_float2(bflo(up), bfhi(up));
    }
}

extern "C" void kernel_launch(void* const* d_in, const int* in_sizes, int n_in,
                              void* d_out, int out_size, void* d_ws, size_t ws_size,
                              hipStream_t stream) {
    const int*   ei = (const int*)d_in[0];
    const float* x  = (const float*)d_in[1];
    const float* Wp = (const float*)d_in[2];
    const float* W1 = (const float*)d_in[3];
    const float* b1 = (const float*)d_in[4];
    const float* W2 = (const float*)d_in[5];
    const float* b2 = (const float*)d_in[6];
    float* out = (float*)d_out;

    const int E = in_sizes[0] / 2;
    const int* erow = ei;
    const int* ecol = ei + E;

    // workspace layout (8B-aligned blocks first)
    char* p = (char*)d_ws;
    u16* H1main = (u16*)p; p += (size_t)MPAD * 128 * 2;  // conv1 h; reused as H2main
    u16* Hcat   = (u16*)p; p += (size_t)MPAD * 160 * 2;  // h1cat bf16, K padded to 160
    u16* Xp1    = (u16*)p; p += (size_t)MPAD * 4 * 2;    // xproj bf16
    u16* H2ext  = (u16*)p; p += (size_t)MPAD * 4 * 2;    // h2 cols 128-131
    u16* W1t    = (u16*)p; p += 144 * 128 * 2;
    u16* W2t    = (u16*)p; p += 144 * 160 * 2;
    u64* ec     = (u64*)p; p += (size_t)E * 8;           // packed (row, coef)
    float* dinv   = (float*)p; p += NN * 4;
    float* invdeg = (float*)p; p += NN * 4;
    int* cnt    = (int*)p; p += NN * 4;
    int* cursor = (int*)p; p += NN * 4;
    int* starts = (int*)p; p += (size_t)(NN + 1) * 4;
    int* tsum   = (int*)p; p += (size_t)SCAN_B * SCAN_T * 4;
    int* bsum   = (int*)p; p += SCAN_B * 4;
    int* bbase  = (int*)p; p += SCAN_B * 4;

    u16* H2main = H1main;  // safe: gemm2 runs after agg1 finished with H1main

    const int T = 256;
    const int eblocks = (E + T - 1) / T;
    const int nblocks = (NN + T - 1) / T;

    // weight prep
    k_prep_w1<<<(144 * 128 + T - 1) / T, T, 0, stream>>>(W1, Wp, W1t);
    k_prep_w2<<<(144 * 160 + T - 1) / T, T, 0, stream>>>(W2, W2t);

    // CSR build
    k_zero_i<<<nblocks, T, 0, stream>>>(cnt, NN);
    k_hist<<<eblocks, T, 0, stream>>>(ecol, E, cnt);
    k_scanA<<<SCAN_B, SCAN_T, 0, stream>>>(cnt, tsum, bsum);
    k_scanB<<<1, 64, 0, stream>>>(bsum, bbase, starts);
    k_scanC<<<SCAN_B, SCAN_T, 0, stream>>>(cnt, tsum, bbase, starts, cursor, dinv, invdeg);
    k_place<<<eblocks, T, 0, stream>>>(erow, ecol, E, cursor, dinv, ec);

    const int gblocks = MPAD / 64;       // 782
    const int ablocks = (NN + 3) / 4;    // 4 waves / block

    // conv1: h = x @ [W1|Wp] (f32 A, in-register bf16 conversion)
    k_gemm_mfma<128, true><<<gblocks, T, 0, stream>>>(x, W1t, H1main, Xp1);
    k_agg1<<<ablocks, T, 0, stream>>>(H1main, Xp1, starts, (const uint2*)ec,
                                      dinv, invdeg, b1, Hcat);

    // conv2
    k_gemm_mfma<160, false><<<gblocks, T, 0, stream>>>(Hcat, W2t, H2main, H2ext);
    k_agg2<<<ablocks, T, 0, stream>>>(H2main, H2ext, Xp1, starts, (const uint2*)ec,
                                      dinv, invdeg, b2, out);
}

// Round 8
// 188.153 us; speedup vs baseline: 6.4369x; 1.2357x over previous
//
#include <hip/hip_runtime.h>

#define NN   50000
#define MPAD 50048   // 782 * 64

#define NB    196    // destination buckets: col >> 8
#define SLOTS 48     // per-bucket LDS staging slots in k_part
#define PT_T  512
#define PT_TILE 4096 // edges per block in k_part / k_bhist
#define CAP   5888   // per-bucket record capacity in k_build
#define BT    256    // k_build threads

typedef __attribute__((ext_vector_type(8))) short bf16x8;
typedef __attribute__((ext_vector_type(4))) float f32x4;
typedef unsigned int  u32;
typedef unsigned short u16;

__device__ __forceinline__ u16 f2bf(float f) {
    u32 u = __float_as_uint(f);
    return (u16)((u + 0x7fffu + ((u >> 16) & 1u)) >> 16);
}
__device__ __forceinline__ float bflo(u32 u) { return __uint_as_float(u << 16); }
__device__ __forceinline__ float bfhi(u32 u) { return __uint_as_float(u & 0xffff0000u); }
__device__ __forceinline__ u32 pack2(float x, float y) {
    return (u32)f2bf(x) | ((u32)f2bf(y) << 16);
}

// ---------------- bucketed CSR build ----------------

__global__ void k_zinit(int* __restrict__ gcnt) {
    int i = threadIdx.x;
    if (i < NB) gcnt[i] = 0;
}

__global__ __launch_bounds__(PT_T) void k_bhist(const int* __restrict__ ecol, int E,
                                                int* __restrict__ gcnt) {
    __shared__ int lh[NB];
    int tid = threadIdx.x;
    for (int i = tid; i < NB; i += PT_T) lh[i] = 0;
    __syncthreads();
    int e0 = blockIdx.x * PT_TILE;
#pragma unroll
    for (int j = 0; j < PT_TILE / PT_T; ++j) {
        int e = e0 + j * PT_T + tid;
        if (e < E) atomicAdd(&lh[ecol[e] >> 8], 1);
    }
    __syncthreads();
    for (int i = tid; i < NB; i += PT_T)
        if (lh[i]) atomicAdd(&gcnt[i], lh[i]);
}

// 1 block, 256 threads: exclusive scan of gcnt[NB] -> gbase[NB+1], init gcursor
__global__ void k_bscan(const int* __restrict__ gcnt, int* __restrict__ gbase,
                        int* __restrict__ gcursor, int* __restrict__ starts, int E) {
    __shared__ int a[256];
    int tid = threadIdx.x;
    int v = (tid < NB) ? gcnt[tid] : 0;
    a[tid] = v;
    __syncthreads();
    for (int off = 1; off < 256; off <<= 1) {
        int add = (tid >= off) ? a[tid - off] : 0;
        __syncthreads();
        a[tid] += add;
        __syncthreads();
    }
    int exc = a[tid] - v;
    if (tid < NB) { gbase[tid] = exc; gcursor[tid] = exc; }
    if (tid == NB - 1) gbase[NB] = a[tid];
    if (tid == 0) starts[NN] = E;
}

// partition: rec = (col&255)<<24 | row  (row needs 17 bits -> use 24-bit field!)
__global__ __launch_bounds__(PT_T) void k_part(const int* __restrict__ erow,
                                               const int* __restrict__ ecol, int E,
                                               int* __restrict__ gcursor,
                                               u32* __restrict__ recs) {
    __shared__ int lcnt[NB];
    __shared__ int bbase[NB];
    __shared__ u32 rbuf[NB * SLOTS];
    int tid = threadIdx.x;
    for (int i = tid; i < NB; i += PT_T) lcnt[i] = 0;
    __syncthreads();
    int e0 = blockIdx.x * PT_TILE;
#pragma unroll
    for (int j = 0; j < PT_TILE / PT_T; ++j) {
        int e = e0 + j * PT_T + tid;
        if (e < E) {
            int c = ecol[e];
            u32 rec = ((u32)(c & 255) << 24) | (u32)erow[e];
            int b = c >> 8;
            int pos = atomicAdd(&lcnt[b], 1);
            if (pos < SLOTS) rbuf[b * SLOTS + pos] = rec;
            else {  // rare overflow: direct global emit
                int g = atomicAdd(&gcursor[b], 1);
                if (g >= 0 && g < E) recs[g] = rec;
            }
        }
    }
    __syncthreads();
    if (tid < NB) {
        int n = lcnt[tid]; if (n > SLOTS) n = SLOTS;
        bbase[tid] = n ? atomicAdd(&gcursor[tid], n) : 0;
    }
    __syncthreads();
    int wave = tid >> 6, lane = tid & 63;
    for (int b = wave; b < NB; b += PT_T / 64) {
        int n = lcnt[b]; if (n > SLOTS) n = SLOTS;
        if (lane < n) {
            int g = bbase[b] + lane;
            if (g >= 0 && g < E) recs[g] = rbuf[b * SLOTS + lane];
        }
    }
}

// per-bucket: count -> scan -> starts/dinv/invdeg -> LDS scatter -> coalesced out
__global__ __launch_bounds__(BT) void k_build(const u32* __restrict__ recs,
                                              const int* __restrict__ gbase,
                                              int* __restrict__ starts,
                                              float* __restrict__ dinv,
                                              float* __restrict__ invdeg,
                                              u32* __restrict__ ec) {
    __shared__ u32 rbuf[CAP];
    __shared__ u32 obuf[CAP];
    __shared__ int ncnt[256];
    __shared__ int a[256];
    __shared__ int ncur[256];
    int tid = threadIdx.x, b = blockIdx.x;
    int lo = gbase[b], hi = gbase[b + 1];
    int cnt = hi - lo;
    bool stage = (cnt > 0) && (cnt <= CAP);
    if (stage) for (int i = tid; i < cnt; i += BT) rbuf[i] = recs[lo + i];
    ncnt[tid] = 0;
    __syncthreads();
    for (int i = tid; i < cnt; i += BT) {
        u32 rec = stage ? rbuf[i] : recs[lo + i];
        atomicAdd(&ncnt[rec >> 24], 1);
    }
    __syncthreads();
    a[tid] = ncnt[tid];
    __syncthreads();
    for (int off = 1; off < 256; off <<= 1) {
        int add = (tid >= off) ? a[tid - off] : 0;
        __syncthreads();
        a[tid] += add;
        __syncthreads();
    }
    int excl = a[tid] - ncnt[tid];
    ncur[tid] = excl;
    {
        int node = (b << 8) + tid;
        if (node < NN) {
            starts[node] = lo + excl;
            float d = (float)ncnt[tid] + 1.0f;
            dinv[node] = rsqrtf(d);
            invdeg[node] = 1.0f / d;
        }
    }
    __syncthreads();
    for (int i = tid; i < cnt; i += BT) {
        u32 rec = stage ? rbuf[i] : recs[lo + i];
        int nl = rec >> 24;
        int pos = atomicAdd(&ncur[nl], 1);
        u32 r = rec & 0xFFFFFFu;
        if (stage) { if (pos >= 0 && pos < CAP) obuf[pos] = r; }
        else if (pos >= 0 && lo + pos < hi) ec[lo + pos] = r;
    }
    __syncthreads();
    if (stage) for (int i = tid; i < cnt; i += BT) ec[lo + i] = obuf[i];
}

// ---------------- weight prep ----------------

__global__ void k_prep_w1(const float* __restrict__ W1, const float* __restrict__ Wp,
                          u16* __restrict__ Wt) {
    int i = blockIdx.x * blockDim.x + threadIdx.x;
    if (i >= 144 * 128) return;
    int n = i >> 7, k = i & 127;
    float v = 0.f;
    if (n < 128) v = W1[k * 128 + n];
    else if (n < 132) v = Wp[k * 4 + (n - 128)];
    Wt[i] = f2bf(v);
}

__global__ void k_prep_w2(const float* __restrict__ W2, u16* __restrict__ Wt) {
    int i = blockIdx.x * blockDim.x + threadIdx.x;
    if (i >= 144 * 160) return;
    int n = i / 160, k = i - n * 160;
    float v = (n < 132 && k < 132) ? W2[k * 132 + n] : 0.f;
    Wt[i] = f2bf(v);
}

// ---------------- MFMA GEMM ----------------
template<int K, bool CONVF32>
__global__ __launch_bounds__(256) void k_gemm_mfma(const void* __restrict__ Ain,
                                                   const u16* __restrict__ Bt,
                                                   u16* __restrict__ Cmain,
                                                   u16* __restrict__ Cext) {
    int lane = threadIdx.x & 63;
    int wv = threadIdx.x >> 6;
    int rbase = blockIdx.x * 64 + wv * 16;
    int lr = lane & 15;
    int kk = (lane >> 4) * 8;
    int arow = rbase + lr;
    if (CONVF32 && arow >= NN) arow = NN - 1;

    const u16* bp = Bt + (size_t)lr * K + kk;

    f32x4 acc[9] = {};
#pragma unroll
    for (int ks = 0; ks < K / 32; ++ks) {
        bf16x8 af;
        if (CONVF32) {
            const float* ap = (const float*)Ain + (size_t)arow * K + kk + ks * 32;
            float4 f0 = *(const float4*)ap;
            float4 f1 = *(const float4*)(ap + 4);
            union { uint4 u; bf16x8 v; } cv;
            cv.u.x = pack2(f0.x, f0.y); cv.u.y = pack2(f0.z, f0.w);
            cv.u.z = pack2(f1.x, f1.y); cv.u.w = pack2(f1.z, f1.w);
            af = cv.v;
        } else {
            af = *(const bf16x8*)((const u16*)Ain + (size_t)arow * K + kk + ks * 32);
        }
#pragma unroll
        for (int t = 0; t < 9; ++t) {
            bf16x8 bf = *(const bf16x8*)(bp + (size_t)(t * 16) * K + ks * 32);
            acc[t] = __builtin_amdgcn_mfma_f32_16x16x32_bf16(bf, af, acc[t], 0, 0, 0);
        }
    }

    int n0 = (lane >> 4) * 4;
    int crow = rbase + lr;
    u16* cm = Cmain + (size_t)crow * 128;
#pragma unroll
    for (int t = 0; t < 8; ++t) {
        ushort4 w;
        w.x = f2bf(acc[t][0]); w.y = f2bf(acc[t][1]);
        w.z = f2bf(acc[t][2]); w.w = f2bf(acc[t][3]);
        *(ushort4*)(cm + 16 * t + n0) = w;
    }
    if (n0 == 0) {
        ushort4 w;
        w.x = f2bf(acc[8][0]); w.y = f2bf(acc[8][1]);
        w.z = f2bf(acc[8][2]); w.w = f2bf(acc[8][3]);
        *(ushort4*)(Cext + (size_t)crow * 4) = w;
    }
}

// ---------------- aggregates (CSR gather, row-only u32 records) ----------------

__global__ void k_agg1(const u16* __restrict__ Hm, const u16* __restrict__ Xp,
                       const int* __restrict__ starts, const u32* __restrict__ ec,
                       const float* __restrict__ dinv, const float* __restrict__ invdeg,
                       const float* __restrict__ b1, u16* __restrict__ outp) {
    int node = blockIdx.x * (blockDim.x >> 6) + (threadIdx.x >> 6);
    int lane = threadIdx.x & 63;
    if (node >= NN) return;
    int s = starts[node], e = starts[node + 1];

    float ax = 0.f, ay = 0.f;
    int i = s;
    for (; i + 4 <= e; i += 4) {
        uint4 q = *(const uint4*)(ec + i);
        float c0 = dinv[q.x], c1 = dinv[q.y], c2 = dinv[q.z], c3 = dinv[q.w];
        u32 u0 = *(const u32*)(Hm + ((size_t)q.x << 7) + 2 * lane);
        u32 u1 = *(const u32*)(Hm + ((size_t)q.y << 7) + 2 * lane);
        u32 u2 = *(const u32*)(Hm + ((size_t)q.z << 7) + 2 * lane);
        u32 u3 = *(const u32*)(Hm + ((size_t)q.w << 7) + 2 * lane);
        ax = fmaf(c0, bflo(u0), ax); ay = fmaf(c0, bfhi(u0), ay);
        ax = fmaf(c1, bflo(u1), ax); ay = fmaf(c1, bfhi(u1), ay);
        ax = fmaf(c2, bflo(u2), ax); ay = fmaf(c2, bfhi(u2), ay);
        ax = fmaf(c3, bflo(u3), ax); ay = fmaf(c3, bfhi(u3), ay);
    }
    for (; i < e; ++i) {
        u32 q = ec[i];
        float c = dinv[q];
        u32 u = *(const u32*)(Hm + ((size_t)q << 7) + 2 * lane);
        ax = fmaf(c, bflo(u), ax); ay = fmaf(c, bfhi(u), ay);
    }

    float dc = dinv[node], idg = invdeg[node];
    u32 us = *(const u32*)(Hm + ((size_t)node << 7) + 2 * lane);
    float2 bv = *(const float2*)(b1 + 2 * lane);
    float vx = fmaxf(fmaf(ax, dc, fmaf(bflo(us), idg, bv.x)), 0.f);
    float vy = fmaxf(fmaf(ay, dc, fmaf(bfhi(us), idg, bv.y)), 0.f);

    u32* orow = (u32*)(outp + (size_t)node * 160);
    orow[lane] = pack2(vx, vy);
    if (lane < 2) orow[64 + lane] = *(const u32*)(Xp + (size_t)node * 4 + 2 * lane);
    else if (lane < 16) orow[64 + lane] = 0;  // zero cols 132..159 (K-pad: NaN guard)
}

__global__ void k_agg2(const u16* __restrict__ Hm, const u16* __restrict__ He,
                       const u16* __restrict__ Xp1,
                       const int* __restrict__ starts, const u32* __restrict__ ec,
                       const float* __restrict__ dinv, const float* __restrict__ invdeg,
                       const float* __restrict__ b2, float* __restrict__ outp) {
    int node = blockIdx.x * (blockDim.x >> 6) + (threadIdx.x >> 6);
    int lane = threadIdx.x & 63;
    if (node >= NN) return;
    int s = starts[node], e = starts[node + 1];

    float ax = 0.f, ay = 0.f, cx = 0.f, cy = 0.f;
    int i = s;
    for (; i + 4 <= e; i += 4) {
        uint4 q = *(const uint4*)(ec + i);
        float c0 = dinv[q.x], c1 = dinv[q.y], c2 = dinv[q.z], c3 = dinv[q.w];
        u32 u0 = *(const u32*)(Hm + ((size_t)q.x << 7) + 2 * lane);
        u32 u1 = *(const u32*)(Hm + ((size_t)q.y << 7) + 2 * lane);
        u32 u2 = *(const u32*)(Hm + ((size_t)q.z << 7) + 2 * lane);
        u32 u3 = *(const u32*)(Hm + ((size_t)q.w << 7) + 2 * lane);
        ax = fmaf(c0, bflo(u0), ax); ay = fmaf(c0, bfhi(u0), ay);
        ax = fmaf(c1, bflo(u1), ax); ay = fmaf(c1, bfhi(u1), ay);
        ax = fmaf(c2, bflo(u2), ax); ay = fmaf(c2, bfhi(u2), ay);
        ax = fmaf(c3, bflo(u3), ax); ay = fmaf(c3, bfhi(u3), ay);
        if (lane < 2) {
            u32 e0 = *(const u32*)(He + ((size_t)q.x << 2) + 2 * lane);
            u32 e1 = *(const u32*)(He + ((size_t)q.y << 2) + 2 * lane);
            u32 e2 = *(const u32*)(He + ((size_t)q.z << 2) + 2 * lane);
            u32 e3 = *(const u32*)(He + ((size_t)q.w << 2) + 2 * lane);
            cx = fmaf(c0, bflo(e0), cx); cy = fmaf(c0, bfhi(e0), cy);
            cx = fmaf(c1, bflo(e1), cx); cy = fmaf(c1, bfhi(e1), cy);
            cx = fmaf(c2, bflo(e2), cx); cy = fmaf(c2, bfhi(e2), cy);
            cx = fmaf(c3, bflo(e3), cx); cy = fmaf(c3, bfhi(e3), cy);
        }
    }
    for (; i < e; ++i) {
        u32 q = ec[i];
        float c = dinv[q];
        u32 u = *(const u32*)(Hm + ((size_t)q << 7) + 2 * lane);
        ax = fmaf(c, bflo(u), ax); ay = fmaf(c, bfhi(u), ay);
        if (lane < 2) {
            u32 e0 = *(const u32*)(He + ((size_t)q << 2) + 2 * lane);
            cx = fmaf(c, bflo(e0), cx); cy = fmaf(c, bfhi(e0), cy);
        }
    }

    float dc = dinv[node], idg = invdeg[node];
    u32 us = *(const u32*)(Hm + ((size_t)node << 7) + 2 * lane);
    float2 bv = *(const float2*)(b2 + 2 * lane);
    float vx = fmaf(ax, dc, fmaf(bflo(us), idg, bv.x));
    float vy = fmaf(ay, dc, fmaf(bfhi(us), idg, bv.y));
    float* orow = outp + (size_t)node * 136;
    *(float2*)(orow + 2 * lane) = make_float2(vx, vy);

    if (lane < 2) {
        u32 us2 = *(const u32*)(He + ((size_t)node << 2) + 2 * lane);
        float2 bb = *(const float2*)(b2 + 128 + 2 * lane);
        float wx = fmaf(cx, dc, fmaf(bflo(us2), idg, bb.x));
        float wy = fmaf(cy, dc, fmaf(bfhi(us2), idg, bb.y));
        *(float2*)(orow + 128 + 2 * lane) = make_float2(wx, wy);
        u32 up = *(const u32*)(Xp1 + ((size_t)node << 2) + 2 * lane);
        *(float2*)(orow + 132 + 2 * lane) = make_float2(bflo(up), bfhi(up));
    }
}

extern "C" void kernel_launch(void* const* d_in, const int* in_sizes, int n_in,
                              void* d_out, int out_size, void* d_ws, size_t ws_size,
                              hipStream_t stream) {
    const int*   ei = (const int*)d_in[0];
    const float* x  = (const float*)d_in[1];
    const float* Wp = (const float*)d_in[2];
    const float* W1 = (const float*)d_in[3];
    const float* b1 = (const float*)d_in[4];
    const float* W2 = (const float*)d_in[5];
    const float* b2 = (const float*)d_in[6];
    float* out = (float*)d_out;

    const int E = in_sizes[0] / 2;
    const int* erow = ei;
    const int* ecol = ei + E;

    // workspace layout (no aliasing)
    char* p = (char*)d_ws;
    u16* H1main = (u16*)p; p += (size_t)MPAD * 128 * 2;  // conv1 h; reused as H2main
    u16* Hcat   = (u16*)p; p += (size_t)MPAD * 160 * 2;  // h1cat bf16
    u16* Xp1    = (u16*)p; p += (size_t)MPAD * 4 * 2;    // xproj bf16
    u16* H2ext  = (u16*)p; p += (size_t)MPAD * 4 * 2;    // h2 cols 128-131
    u16* W1t    = (u16*)p; p += 144 * 128 * 2;
    u16* W2t    = (u16*)p; p += 144 * 160 * 2;
    u32* recs   = (u32*)p; p += (size_t)E * 4;           // bucketed records
    u32* ec     = (u32*)p; p += (size_t)E * 4;           // sorted row-only records
    float* dinv   = (float*)p; p += NN * 4;
    float* invdeg = (float*)p; p += NN * 4;
    int* starts = (int*)p; p += (size_t)(NN + 1) * 4;
    int* gcnt   = (int*)p; p += NB * 4;
    int* gbase  = (int*)p; p += (NB + 1) * 4;
    int* gcursor= (int*)p; p += NB * 4;

    u16* H2main = H1main;

    const int T = 256;
    const int pblocks = (E + PT_TILE - 1) / PT_TILE;

    // weight prep
    k_prep_w1<<<(144 * 128 + T - 1) / T, T, 0, stream>>>(W1, Wp, W1t);
    k_prep_w2<<<(144 * 160 + T - 1) / T, T, 0, stream>>>(W2, W2t);

    // bucketed CSR build
    k_zinit<<<1, 256, 0, stream>>>(gcnt);
    k_bhist<<<pblocks, PT_T, 0, stream>>>(ecol, E, gcnt);
    k_bscan<<<1, 256, 0, stream>>>(gcnt, gbase, gcursor, starts, E);
    k_part<<<pblocks, PT_T, 0, stream>>>(erow, ecol, E, gcursor, recs);
    k_build<<<NB, BT, 0, stream>>>(recs, gbase, starts, dinv, invdeg, ec);

    const int gblocks = MPAD / 64;
    const int ablocks = (NN + 3) / 4;

    // conv1: h = x @ [W1|Wp] (f32 A, in-register bf16 conversion)
    k_gemm_mfma<128, true><<<gblocks, T, 0, stream>>>(x, W1t, H1main, Xp1);
    k_agg1<<<ablocks, T, 0, stream>>>(H1main, Xp1, starts, ec, dinv, invdeg, b1, Hcat);

    // conv2
    k_gemm_mfma<160, false><<<gblocks, T, 0, stream>>>(Hcat, W2t, H2main, H2ext);
    k_agg2<<<ablocks, T, 0, stream>>>(H2main, H2ext, Xp1, starts, ec, dinv, invdeg, b2, out);
}

// Round 9
// 173.654 us; speedup vs baseline: 6.9743x; 1.0835x over previous
//
#include <hip/hip_runtime.h>

#define NN   50000
#define MPAD 50048   // 782 * 64

#define NB    196    // destination buckets: col >> 8
#define SLOTS 48     // per-bucket LDS staging slots in k_part
#define PT_T  512
#define PT_TILE 4096 // edges per block in k_part / k_bhist
#define CAP   5888   // per-bucket record capacity in k_build
#define BT    256    // k_build threads

typedef __attribute__((ext_vector_type(8))) short bf16x8;
typedef __attribute__((ext_vector_type(4))) float f32x4;
typedef unsigned int  u32;
typedef unsigned short u16;

__device__ __forceinline__ u16 f2bf(float f) {
    u32 u = __float_as_uint(f);
    return (u16)((u + 0x7fffu + ((u >> 16) & 1u)) >> 16);
}
__device__ __forceinline__ float bflo(u32 u) { return __uint_as_float(u << 16); }
__device__ __forceinline__ float bfhi(u32 u) { return __uint_as_float(u & 0xffff0000u); }
__device__ __forceinline__ u32 pack2(float x, float y) {
    return (u32)f2bf(x) | ((u32)f2bf(y) << 16);
}

// ---------------- bucketed CSR build ----------------

__global__ void k_zinit(int* __restrict__ gcnt) {
    int i = threadIdx.x;
    if (i < NB) gcnt[i] = 0;
}

__global__ __launch_bounds__(PT_T) void k_bhist(const int* __restrict__ ecol, int E,
                                                int* __restrict__ gcnt) {
    __shared__ int lh[NB];
    int tid = threadIdx.x;
    for (int i = tid; i < NB; i += PT_T) lh[i] = 0;
    __syncthreads();
    int e0 = blockIdx.x * PT_TILE;
#pragma unroll
    for (int j = 0; j < PT_TILE / PT_T; ++j) {
        int e = e0 + j * PT_T + tid;
        if (e < E) atomicAdd(&lh[ecol[e] >> 8], 1);
    }
    __syncthreads();
    for (int i = tid; i < NB; i += PT_T)
        if (lh[i]) atomicAdd(&gcnt[i], lh[i]);
}

// 1 block, 256 threads: exclusive scan of gcnt[NB] -> gbase[NB+1], init gcursor
__global__ void k_bscan(const int* __restrict__ gcnt, int* __restrict__ gbase,
                        int* __restrict__ gcursor, int* __restrict__ starts, int E) {
    __shared__ int a[256];
    int tid = threadIdx.x;
    int v = (tid < NB) ? gcnt[tid] : 0;
    a[tid] = v;
    __syncthreads();
    for (int off = 1; off < 256; off <<= 1) {
        int add = (tid >= off) ? a[tid - off] : 0;
        __syncthreads();
        a[tid] += add;
        __syncthreads();
    }
    int exc = a[tid] - v;
    if (tid < NB) { gbase[tid] = exc; gcursor[tid] = exc; }
    if (tid == NB - 1) gbase[NB] = a[tid];
    if (tid == 0) starts[NN] = E;
}

// partition: rec = (col&255)<<24 | row  (row needs 17 bits -> 24-bit field)
__global__ __launch_bounds__(PT_T) void k_part(const int* __restrict__ erow,
                                               const int* __restrict__ ecol, int E,
                                               int* __restrict__ gcursor,
                                               u32* __restrict__ recs) {
    __shared__ int lcnt[NB];
    __shared__ int bbase[NB];
    __shared__ u32 rbuf[NB * SLOTS];
    int tid = threadIdx.x;
    for (int i = tid; i < NB; i += PT_T) lcnt[i] = 0;
    __syncthreads();
    int e0 = blockIdx.x * PT_TILE;
#pragma unroll
    for (int j = 0; j < PT_TILE / PT_T; ++j) {
        int e = e0 + j * PT_T + tid;
        if (e < E) {
            int c = ecol[e];
            u32 rec = ((u32)(c & 255) << 24) | (u32)erow[e];
            int b = c >> 8;
            int pos = atomicAdd(&lcnt[b], 1);
            if (pos < SLOTS) rbuf[b * SLOTS + pos] = rec;
            else {
                int g = atomicAdd(&gcursor[b], 1);
                if (g >= 0 && g < E) recs[g] = rec;
            }
        }
    }
    __syncthreads();
    if (tid < NB) {
        int n = lcnt[tid]; if (n > SLOTS) n = SLOTS;
        bbase[tid] = n ? atomicAdd(&gcursor[tid], n) : 0;
    }
    __syncthreads();
    int wave = tid >> 6, lane = tid & 63;
    for (int b = wave; b < NB; b += PT_T / 64) {
        int n = lcnt[b]; if (n > SLOTS) n = SLOTS;
        if (lane < n) {
            int g = bbase[b] + lane;
            if (g >= 0 && g < E) recs[g] = rbuf[b * SLOTS + lane];
        }
    }
}

// per-bucket: count -> scan -> starts/dinv -> LDS scatter -> coalesced out
__global__ __launch_bounds__(BT) void k_build(const u32* __restrict__ recs,
                                              const int* __restrict__ gbase,
                                              int* __restrict__ starts,
                                              float* __restrict__ dinv,
                                              u32* __restrict__ ec) {
    __shared__ u32 rbuf[CAP];
    __shared__ u32 obuf[CAP];
    __shared__ int ncnt[256];
    __shared__ int a[256];
    __shared__ int ncur[256];
    int tid = threadIdx.x, b = blockIdx.x;
    int lo = gbase[b], hi = gbase[b + 1];
    int cnt = hi - lo;
    bool stage = (cnt > 0) && (cnt <= CAP);
    if (stage) for (int i = tid; i < cnt; i += BT) rbuf[i] = recs[lo + i];
    ncnt[tid] = 0;
    __syncthreads();
    for (int i = tid; i < cnt; i += BT) {
        u32 rec = stage ? rbuf[i] : recs[lo + i];
        atomicAdd(&ncnt[rec >> 24], 1);
    }
    __syncthreads();
    a[tid] = ncnt[tid];
    __syncthreads();
    for (int off = 1; off < 256; off <<= 1) {
        int add = (tid >= off) ? a[tid - off] : 0;
        __syncthreads();
        a[tid] += add;
        __syncthreads();
    }
    int excl = a[tid] - ncnt[tid];
    ncur[tid] = excl;
    {
        int node = (b << 8) + tid;
        if (node < NN) {
            starts[node] = lo + excl;
            float d = (float)ncnt[tid] + 1.0f;
            dinv[node] = rsqrtf(d);
        }
    }
    __syncthreads();
    for (int i = tid; i < cnt; i += BT) {
        u32 rec = stage ? rbuf[i] : recs[lo + i];
        int nl = rec >> 24;
        int pos = atomicAdd(&ncur[nl], 1);
        u32 r = rec & 0xFFFFFFu;
        if (stage) { if (pos >= 0 && pos < CAP) obuf[pos] = r; }
        else if (pos >= 0 && lo + pos < hi) ec[lo + pos] = r;
    }
    __syncthreads();
    if (stage) for (int i = tid; i < cnt; i += BT) ec[lo + i] = obuf[i];
}

// ---------------- weight prep ----------------

__global__ void k_prep_w1(const float* __restrict__ W1, const float* __restrict__ Wp,
                          u16* __restrict__ Wt) {
    int i = blockIdx.x * blockDim.x + threadIdx.x;
    if (i >= 144 * 128) return;
    int n = i >> 7, k = i & 127;
    float v = 0.f;
    if (n < 128) v = W1[k * 128 + n];
    else if (n < 132) v = Wp[k * 4 + (n - 128)];
    Wt[i] = f2bf(v);
}

__global__ void k_prep_w2(const float* __restrict__ W2, u16* __restrict__ Wt) {
    int i = blockIdx.x * blockDim.x + threadIdx.x;
    if (i >= 144 * 160) return;
    int n = i / 160, k = i - n * 160;
    float v = (n < 132 && k < 132) ? W2[k * 132 + n] : 0.f;
    Wt[i] = f2bf(v);
}

// ---------------- MFMA GEMM with fused dinv row-scaling ----------------
// Cmain rows scaled by dinv[row]; Cext scaled only if SCALE_EXT (xproj must stay raw).
template<int K, bool CONVF32, bool SCALE_EXT>
__global__ __launch_bounds__(256) void k_gemm_mfma(const void* __restrict__ Ain,
                                                   const u16* __restrict__ Bt,
                                                   const float* __restrict__ rs,
                                                   u16* __restrict__ Cmain,
                                                   u16* __restrict__ Cext) {
    int lane = threadIdx.x & 63;
    int wv = threadIdx.x >> 6;
    int rbase = blockIdx.x * 64 + wv * 16;
    int lr = lane & 15;
    int kk = (lane >> 4) * 8;
    int arow = rbase + lr;
    if (CONVF32 && arow >= NN) arow = NN - 1;

    const u16* bp = Bt + (size_t)lr * K + kk;

    f32x4 acc[9] = {};
#pragma unroll
    for (int ks = 0; ks < K / 32; ++ks) {
        bf16x8 af;
        if (CONVF32) {
            const float* ap = (const float*)Ain + (size_t)arow * K + kk + ks * 32;
            float4 f0 = *(const float4*)ap;
            float4 f1 = *(const float4*)(ap + 4);
            union { uint4 u; bf16x8 v; } cv;
            cv.u.x = pack2(f0.x, f0.y); cv.u.y = pack2(f0.z, f0.w);
            cv.u.z = pack2(f1.x, f1.y); cv.u.w = pack2(f1.z, f1.w);
            af = cv.v;
        } else {
            af = *(const bf16x8*)((const u16*)Ain + (size_t)arow * K + kk + ks * 32);
        }
#pragma unroll
        for (int t = 0; t < 9; ++t) {
            bf16x8 bf = *(const bf16x8*)(bp + (size_t)(t * 16) * K + ks * 32);
            acc[t] = __builtin_amdgcn_mfma_f32_16x16x32_bf16(bf, af, acc[t], 0, 0, 0);
        }
    }

    int n0 = (lane >> 4) * 4;
    int crow = rbase + lr;
    int srow = crow < NN ? crow : NN - 1;
    float s = rs[srow];
    u16* cm = Cmain + (size_t)crow * 128;
#pragma unroll
    for (int t = 0; t < 8; ++t) {
        ushort4 w;
        w.x = f2bf(acc[t][0] * s); w.y = f2bf(acc[t][1] * s);
        w.z = f2bf(acc[t][2] * s); w.w = f2bf(acc[t][3] * s);
        *(ushort4*)(cm + 16 * t + n0) = w;
    }
    if (n0 == 0) {
        float se = SCALE_EXT ? s : 1.0f;
        ushort4 w;
        w.x = f2bf(acc[8][0] * se); w.y = f2bf(acc[8][1] * se);
        w.z = f2bf(acc[8][2] * se); w.w = f2bf(acc[8][3] * se);
        *(ushort4*)(Cext + (size_t)crow * 4) = w;
    }
}

// ---------------- aggregates: rows pre-scaled -> pure adds ----------------
// out_node = dinv[node] * (sum_edges h'[r] + h'[node]) + bias

__global__ void k_agg1(const u16* __restrict__ Hm, const u16* __restrict__ Xp,
                       const int* __restrict__ starts, const u32* __restrict__ ec,
                       const float* __restrict__ dinv,
                       const float* __restrict__ b1, u16* __restrict__ outp) {
    int node = blockIdx.x * (blockDim.x >> 6) + (threadIdx.x >> 6);
    int lane = threadIdx.x & 63;
    if (node >= NN) return;
    int s = starts[node], e = starts[node + 1];

    u32 us = *(const u32*)(Hm + ((size_t)node << 7) + 2 * lane);
    float ax = bflo(us), ay = bfhi(us);
    int i = s;
    for (; i + 8 <= e; i += 8) {
        uint4 qa = *(const uint4*)(ec + i);
        uint4 qb = *(const uint4*)(ec + i + 4);
        u32 u0 = *(const u32*)(Hm + ((size_t)qa.x << 7) + 2 * lane);
        u32 u1 = *(const u32*)(Hm + ((size_t)qa.y << 7) + 2 * lane);
        u32 u2 = *(const u32*)(Hm + ((size_t)qa.z << 7) + 2 * lane);
        u32 u3 = *(const u32*)(Hm + ((size_t)qa.w << 7) + 2 * lane);
        u32 u4 = *(const u32*)(Hm + ((size_t)qb.x << 7) + 2 * lane);
        u32 u5 = *(const u32*)(Hm + ((size_t)qb.y << 7) + 2 * lane);
        u32 u6 = *(const u32*)(Hm + ((size_t)qb.z << 7) + 2 * lane);
        u32 u7 = *(const u32*)(Hm + ((size_t)qb.w << 7) + 2 * lane);
        ax += bflo(u0); ay += bfhi(u0); ax += bflo(u1); ay += bfhi(u1);
        ax += bflo(u2); ay += bfhi(u2); ax += bflo(u3); ay += bfhi(u3);
        ax += bflo(u4); ay += bfhi(u4); ax += bflo(u5); ay += bfhi(u5);
        ax += bflo(u6); ay += bfhi(u6); ax += bflo(u7); ay += bfhi(u7);
    }
    for (; i + 4 <= e; i += 4) {
        uint4 q = *(const uint4*)(ec + i);
        u32 u0 = *(const u32*)(Hm + ((size_t)q.x << 7) + 2 * lane);
        u32 u1 = *(const u32*)(Hm + ((size_t)q.y << 7) + 2 * lane);
        u32 u2 = *(const u32*)(Hm + ((size_t)q.z << 7) + 2 * lane);
        u32 u3 = *(const u32*)(Hm + ((size_t)q.w << 7) + 2 * lane);
        ax += bflo(u0); ay += bfhi(u0); ax += bflo(u1); ay += bfhi(u1);
        ax += bflo(u2); ay += bfhi(u2); ax += bflo(u3); ay += bfhi(u3);
    }
    for (; i < e; ++i) {
        u32 q = ec[i];
        u32 u = *(const u32*)(Hm + ((size_t)q << 7) + 2 * lane);
        ax += bflo(u); ay += bfhi(u);
    }

    float dc = dinv[node];
    float2 bv = *(const float2*)(b1 + 2 * lane);
    float vx = fmaxf(fmaf(dc, ax, bv.x), 0.f);
    float vy = fmaxf(fmaf(dc, ay, bv.y), 0.f);

    u32* orow = (u32*)(outp + (size_t)node * 160);
    orow[lane] = pack2(vx, vy);
    if (lane < 2) orow[64 + lane] = *(const u32*)(Xp + (size_t)node * 4 + 2 * lane);
    else if (lane < 16) orow[64 + lane] = 0;  // zero cols 132..159 (K-pad NaN guard)
}

__global__ void k_agg2(const u16* __restrict__ Hm, const u16* __restrict__ He,
                       const u16* __restrict__ Xp1,
                       const int* __restrict__ starts, const u32* __restrict__ ec,
                       const float* __restrict__ dinv,
                       const float* __restrict__ b2, float* __restrict__ outp) {
    int node = blockIdx.x * (blockDim.x >> 6) + (threadIdx.x >> 6);
    int lane = threadIdx.x & 63;
    if (node >= NN) return;
    int s = starts[node], e = starts[node + 1];

    u32 us = *(const u32*)(Hm + ((size_t)node << 7) + 2 * lane);
    float ax = bflo(us), ay = bfhi(us);
    float cx = 0.f, cy = 0.f;
    if (lane < 2) {
        u32 us2 = *(const u32*)(He + ((size_t)node << 2) + 2 * lane);
        cx = bflo(us2); cy = bfhi(us2);
    }
    int i = s;
    for (; i + 8 <= e; i += 8) {
        uint4 qa = *(const uint4*)(ec + i);
        uint4 qb = *(const uint4*)(ec + i + 4);
        u32 u0 = *(const u32*)(Hm + ((size_t)qa.x << 7) + 2 * lane);
        u32 u1 = *(const u32*)(Hm + ((size_t)qa.y << 7) + 2 * lane);
        u32 u2 = *(const u32*)(Hm + ((size_t)qa.z << 7) + 2 * lane);
        u32 u3 = *(const u32*)(Hm + ((size_t)qa.w << 7) + 2 * lane);
        u32 u4 = *(const u32*)(Hm + ((size_t)qb.x << 7) + 2 * lane);
        u32 u5 = *(const u32*)(Hm + ((size_t)qb.y << 7) + 2 * lane);
        u32 u6 = *(const u32*)(Hm + ((size_t)qb.z << 7) + 2 * lane);
        u32 u7 = *(const u32*)(Hm + ((size_t)qb.w << 7) + 2 * lane);
        ax += bflo(u0); ay += bfhi(u0); ax += bflo(u1); ay += bfhi(u1);
        ax += bflo(u2); ay += bfhi(u2); ax += bflo(u3); ay += bfhi(u3);
        ax += bflo(u4); ay += bfhi(u4); ax += bflo(u5); ay += bfhi(u5);
        ax += bflo(u6); ay += bfhi(u6); ax += bflo(u7); ay += bfhi(u7);
        if (lane < 2) {
            u32 e0 = *(const u32*)(He + ((size_t)qa.x << 2) + 2 * lane);
            u32 e1 = *(const u32*)(He + ((size_t)qa.y << 2) + 2 * lane);
            u32 e2 = *(const u32*)(He + ((size_t)qa.z << 2) + 2 * lane);
            u32 e3 = *(const u32*)(He + ((size_t)qa.w << 2) + 2 * lane);
            u32 e4 = *(const u32*)(He + ((size_t)qb.x << 2) + 2 * lane);
            u32 e5 = *(const u32*)(He + ((size_t)qb.y << 2) + 2 * lane);
            u32 e6 = *(const u32*)(He + ((size_t)qb.z << 2) + 2 * lane);
            u32 e7 = *(const u32*)(He + ((size_t)qb.w << 2) + 2 * lane);
            cx += bflo(e0); cy += bfhi(e0); cx += bflo(e1); cy += bfhi(e1);
            cx += bflo(e2); cy += bfhi(e2); cx += bflo(e3); cy += bfhi(e3);
            cx += bflo(e4); cy += bfhi(e4); cx += bflo(e5); cy += bfhi(e5);
            cx += bflo(e6); cy += bfhi(e6); cx += bflo(e7); cy += bfhi(e7);
        }
    }
    for (; i < e; ++i) {
        u32 q = ec[i];
        u32 u = *(const u32*)(Hm + ((size_t)q << 7) + 2 * lane);
        ax += bflo(u); ay += bfhi(u);
        if (lane < 2) {
            u32 e0 = *(const u32*)(He + ((size_t)q << 2) + 2 * lane);
            cx += bflo(e0); cy += bfhi(e0);
        }
    }

    float dc = dinv[node];
    float2 bv = *(const float2*)(b2 + 2 * lane);
    float vx = fmaf(dc, ax, bv.x);
    float vy = fmaf(dc, ay, bv.y);
    float* orow = outp + (size_t)node * 136;
    *(float2*)(orow + 2 * lane) = make_float2(vx, vy);

    if (lane < 2) {
        float2 bb = *(const float2*)(b2 + 128 + 2 * lane);
        float wx = fmaf(dc, cx, bb.x);
        float wy = fmaf(dc, cy, bb.y);
        *(float2*)(orow + 128 + 2 * lane) = make_float2(wx, wy);
        u32 up = *(const u32*)(Xp1 + ((size_t)node << 2) + 2 * lane);
        *(float2*)(orow + 132 + 2 * lane) = make_float2(bflo(up), bfhi(up));
    }
}

extern "C" void kernel_launch(void* const* d_in, const int* in_sizes, int n_in,
                              void* d_out, int out_size, void* d_ws, size_t ws_size,
                              hipStream_t stream) {
    const int*   ei = (const int*)d_in[0];
    const float* x  = (const float*)d_in[1];
    const float* Wp = (const float*)d_in[2];
    const float* W1 = (const float*)d_in[3];
    const float* b1 = (const float*)d_in[4];
    const float* W2 = (const float*)d_in[5];
    const float* b2 = (const float*)d_in[6];
    float* out = (float*)d_out;

    const int E = in_sizes[0] / 2;
    const int* erow = ei;
    const int* ecol = ei + E;

    // workspace layout (no aliasing)
    char* p = (char*)d_ws;
    u16* H1main = (u16*)p; p += (size_t)MPAD * 128 * 2;  // conv1 h' (scaled); reused as H2main
    u16* Hcat   = (u16*)p; p += (size_t)MPAD * 160 * 2;  // h1cat bf16 (unscaled)
    u16* Xp1    = (u16*)p; p += (size_t)MPAD * 4 * 2;    // xproj bf16 (unscaled)
    u16* H2ext  = (u16*)p; p += (size_t)MPAD * 4 * 2;    // h2' cols 128-131 (scaled)
    u16* W1t    = (u16*)p; p += 144 * 128 * 2;
    u16* W2t    = (u16*)p; p += 144 * 160 * 2;
    u32* recs   = (u32*)p; p += (size_t)E * 4;           // bucketed records
    u32* ec     = (u32*)p; p += (size_t)E * 4;           // sorted row-only records
    float* dinv   = (float*)p; p += NN * 4;
    int* starts = (int*)p; p += (size_t)(NN + 1) * 4;
    int* gcnt   = (int*)p; p += NB * 4;
    int* gbase  = (int*)p; p += (NB + 1) * 4;
    int* gcursor= (int*)p; p += NB * 4;

    u16* H2main = H1main;

    const int T = 256;
    const int pblocks = (E + PT_TILE - 1) / PT_TILE;

    // weight prep
    k_prep_w1<<<(144 * 128 + T - 1) / T, T, 0, stream>>>(W1, Wp, W1t);
    k_prep_w2<<<(144 * 160 + T - 1) / T, T, 0, stream>>>(W2, W2t);

    // bucketed CSR build
    k_zinit<<<1, 256, 0, stream>>>(gcnt);
    k_bhist<<<pblocks, PT_T, 0, stream>>>(ecol, E, gcnt);
    k_bscan<<<1, 256, 0, stream>>>(gcnt, gbase, gcursor, starts, E);
    k_part<<<pblocks, PT_T, 0, stream>>>(erow, ecol, E, gcursor, recs);
    k_build<<<NB, BT, 0, stream>>>(recs, gbase, starts, dinv, ec);

    const int gblocks = MPAD / 64;
    const int ablocks = (NN + 3) / 4;

    // conv1: h' = dinv .* (x @ [W1|Wp]) ; xproj raw
    k_gemm_mfma<128, true, false><<<gblocks, T, 0, stream>>>(x, W1t, dinv, H1main, Xp1);
    k_agg1<<<ablocks, T, 0, stream>>>(H1main, Xp1, starts, ec, dinv, b1, Hcat);

    // conv2: h2' = dinv .* (h1cat @ W2), ext cols scaled too
    k_gemm_mfma<160, false, true><<<gblocks, T, 0, stream>>>(Hcat, W2t, dinv, H2main, H2ext);
    k_agg2<<<ablocks, T, 0, stream>>>(H2main, H2ext, Xp1, starts, ec, dinv, b2, out);
}

// Round 10
// 159.893 us; speedup vs baseline: 7.5745x; 1.0861x over previous
//
#include <hip/hip_runtime.h>

#define NN   50000
#define MPAD 50048   // 782 * 64
#define ZR   NN      // zero-row index (gemm writes zeros there via scale=0)

#define NB    196    // destination buckets: col >> 8
#define SLOTS 48
#define PT_T  512
#define PT_TILE 4096
#define CAP   5888
#define BT    256

typedef __attribute__((ext_vector_type(8))) short bf16x8;
typedef __attribute__((ext_vector_type(4))) float f32x4;
typedef unsigned int  u32;
typedef unsigned short u16;

__device__ __forceinline__ u16 f2bf(float f) {
    u32 u = __float_as_uint(f);
    return (u16)((u + 0x7fffu + ((u >> 16) & 1u)) >> 16);
}
__device__ __forceinline__ float bflo(u32 u) { return __uint_as_float(u << 16); }
__device__ __forceinline__ float bfhi(u32 u) { return __uint_as_float(u & 0xffff0000u); }
__device__ __forceinline__ u32 pack2(float x, float y) {
    return (u32)f2bf(x) | ((u32)f2bf(y) << 16);
}

// ---------------- bucketed CSR build ----------------

__global__ void k_zinit(int* __restrict__ gcnt) {
    int i = threadIdx.x;
    if (i < NB) gcnt[i] = 0;
}

__global__ __launch_bounds__(PT_T) void k_bhist(const int* __restrict__ ecol, int E,
                                                int* __restrict__ gcnt) {
    __shared__ int lh[NB];
    int tid = threadIdx.x;
    for (int i = tid; i < NB; i += PT_T) lh[i] = 0;
    __syncthreads();
    int e0 = blockIdx.x * PT_TILE;
#pragma unroll
    for (int j = 0; j < PT_TILE / PT_T; ++j) {
        int e = e0 + j * PT_T + tid;
        if (e < E) atomicAdd(&lh[ecol[e] >> 8], 1);
    }
    __syncthreads();
    for (int i = tid; i < NB; i += PT_T)
        if (lh[i]) atomicAdd(&gcnt[i], lh[i]);
}

__global__ void k_bscan(const int* __restrict__ gcnt, int* __restrict__ gbase,
                        int* __restrict__ gcursor, int* __restrict__ starts, int E) {
    __shared__ int a[256];
    int tid = threadIdx.x;
    int v = (tid < NB) ? gcnt[tid] : 0;
    a[tid] = v;
    __syncthreads();
    for (int off = 1; off < 256; off <<= 1) {
        int add = (tid >= off) ? a[tid - off] : 0;
        __syncthreads();
        a[tid] += add;
        __syncthreads();
    }
    int exc = a[tid] - v;
    if (tid < NB) { gbase[tid] = exc; gcursor[tid] = exc; }
    if (tid == NB - 1) gbase[NB] = a[tid];
    if (tid == 0) starts[NN] = E;
}

// rec = (col&255)<<24 | row
__global__ __launch_bounds__(PT_T) void k_part(const int* __restrict__ erow,
                                               const int* __restrict__ ecol, int E,
                                               int* __restrict__ gcursor,
                                               u32* __restrict__ recs) {
    __shared__ int lcnt[NB];
    __shared__ int bbase[NB];
    __shared__ u32 rbuf[NB * SLOTS];
    int tid = threadIdx.x;
    for (int i = tid; i < NB; i += PT_T) lcnt[i] = 0;
    __syncthreads();
    int e0 = blockIdx.x * PT_TILE;
#pragma unroll
    for (int j = 0; j < PT_TILE / PT_T; ++j) {
        int e = e0 + j * PT_T + tid;
        if (e < E) {
            int c = ecol[e];
            u32 rec = ((u32)(c & 255) << 24) | (u32)erow[e];
            int b = c >> 8;
            int pos = atomicAdd(&lcnt[b], 1);
            if (pos < SLOTS) rbuf[b * SLOTS + pos] = rec;
            else {
                int g = atomicAdd(&gcursor[b], 1);
                if (g >= 0 && g < E) recs[g] = rec;
            }
        }
    }
    __syncthreads();
    if (tid < NB) {
        int n = lcnt[tid]; if (n > SLOTS) n = SLOTS;
        bbase[tid] = n ? atomicAdd(&gcursor[tid], n) : 0;
    }
    __syncthreads();
    int wave = tid >> 6, lane = tid & 63;
    for (int b = wave; b < NB; b += PT_T / 64) {
        int n = lcnt[b]; if (n > SLOTS) n = SLOTS;
        if (lane < n) {
            int g = bbase[b] + lane;
            if (g >= 0 && g < E) recs[g] = rbuf[b * SLOTS + lane];
        }
    }
}

__global__ __launch_bounds__(BT) void k_build(const u32* __restrict__ recs,
                                              const int* __restrict__ gbase,
                                              int* __restrict__ starts,
                                              float* __restrict__ dinv,
                                              u32* __restrict__ ec) {
    __shared__ u32 rbuf[CAP];
    __shared__ u32 obuf[CAP];
    __shared__ int ncnt[256];
    __shared__ int a[256];
    __shared__ int ncur[256];
    int tid = threadIdx.x, b = blockIdx.x;
    int lo = gbase[b], hi = gbase[b + 1];
    int cnt = hi - lo;
    bool stage = (cnt > 0) && (cnt <= CAP);
    if (stage) for (int i = tid; i < cnt; i += BT) rbuf[i] = recs[lo + i];
    ncnt[tid] = 0;
    __syncthreads();
    for (int i = tid; i < cnt; i += BT) {
        u32 rec = stage ? rbuf[i] : recs[lo + i];
        atomicAdd(&ncnt[rec >> 24], 1);
    }
    __syncthreads();
    a[tid] = ncnt[tid];
    __syncthreads();
    for (int off = 1; off < 256; off <<= 1) {
        int add = (tid >= off) ? a[tid - off] : 0;
        __syncthreads();
        a[tid] += add;
        __syncthreads();
    }
    int excl = a[tid] - ncnt[tid];
    ncur[tid] = excl;
    {
        int node = (b << 8) + tid;
        if (node < NN) {
            starts[node] = lo + excl;
            float d = (float)ncnt[tid] + 1.0f;
            dinv[node] = rsqrtf(d);
        }
    }
    __syncthreads();
    for (int i = tid; i < cnt; i += BT) {
        u32 rec = stage ? rbuf[i] : recs[lo + i];
        int nl = rec >> 24;
        int pos = atomicAdd(&ncur[nl], 1);
        u32 r = rec & 0xFFFFFFu;
        if (stage) { if (pos >= 0 && pos < CAP) obuf[pos] = r; }
        else if (pos >= 0 && lo + pos < hi) ec[lo + pos] = r;
    }
    __syncthreads();
    if (stage) for (int i = tid; i < cnt; i += BT) ec[lo + i] = obuf[i];
}

// ---------------- weight prep ----------------

__global__ void k_prep_w1(const float* __restrict__ W1, const float* __restrict__ Wp,
                          u16* __restrict__ Wt) {
    int i = blockIdx.x * blockDim.x + threadIdx.x;
    if (i >= 144 * 128) return;
    int n = i >> 7, k = i & 127;
    float v = 0.f;
    if (n < 128) v = W1[k * 128 + n];
    else if (n < 132) v = Wp[k * 4 + (n - 128)];
    Wt[i] = f2bf(v);
}

__global__ void k_prep_w2(const float* __restrict__ W2, u16* __restrict__ Wt) {
    int i = blockIdx.x * blockDim.x + threadIdx.x;
    if (i >= 144 * 160) return;
    int n = i / 160, k = i - n * 160;
    float v = (n < 132 && k < 132) ? W2[k * 132 + n] : 0.f;
    Wt[i] = f2bf(v);
}

// ---------------- MFMA GEMM, fused dinv row-scaling; pad rows scale=0 -> zeros ----------------
template<int K, bool CONVF32, bool SCALE_EXT>
__global__ __launch_bounds__(256) void k_gemm_mfma(const void* __restrict__ Ain,
                                                   const u16* __restrict__ Bt,
                                                   const float* __restrict__ rs,
                                                   u16* __restrict__ Cmain,
                                                   u16* __restrict__ Cext) {
    int lane = threadIdx.x & 63;
    int wv = threadIdx.x >> 6;
    int rbase = blockIdx.x * 64 + wv * 16;
    int lr = lane & 15;
    int kk = (lane >> 4) * 8;
    int arow = rbase + lr;
    if (CONVF32 && arow >= NN) arow = NN - 1;

    const u16* bp = Bt + (size_t)lr * K + kk;

    f32x4 acc[9] = {};
#pragma unroll
    for (int ks = 0; ks < K / 32; ++ks) {
        bf16x8 af;
        if (CONVF32) {
            const float* ap = (const float*)Ain + (size_t)arow * K + kk + ks * 32;
            float4 f0 = *(const float4*)ap;
            float4 f1 = *(const float4*)(ap + 4);
            union { uint4 u; bf16x8 v; } cv;
            cv.u.x = pack2(f0.x, f0.y); cv.u.y = pack2(f0.z, f0.w);
            cv.u.z = pack2(f1.x, f1.y); cv.u.w = pack2(f1.z, f1.w);
            af = cv.v;
        } else {
            af = *(const bf16x8*)((const u16*)Ain + (size_t)arow * K + kk + ks * 32);
        }
#pragma unroll
        for (int t = 0; t < 9; ++t) {
            bf16x8 bf = *(const bf16x8*)(bp + (size_t)(t * 16) * K + ks * 32);
            acc[t] = __builtin_amdgcn_mfma_f32_16x16x32_bf16(bf, af, acc[t], 0, 0, 0);
        }
    }

    int n0 = (lane >> 4) * 4;
    int crow = rbase + lr;
    float s = (crow < NN) ? rs[crow] : 0.0f;   // pad rows -> exact zeros
    u16* cm = Cmain + (size_t)crow * 128;
#pragma unroll
    for (int t = 0; t < 8; ++t) {
        ushort4 w;
        w.x = f2bf(acc[t][0] * s); w.y = f2bf(acc[t][1] * s);
        w.z = f2bf(acc[t][2] * s); w.w = f2bf(acc[t][3] * s);
        *(ushort4*)(cm + 16 * t + n0) = w;
    }
    if (n0 == 0) {
        float se = SCALE_EXT ? s : ((crow < NN) ? 1.0f : 0.0f);
        ushort4 w;
        w.x = f2bf(acc[8][0] * se); w.y = f2bf(acc[8][1] * se);
        w.z = f2bf(acc[8][2] * se); w.w = f2bf(acc[8][3] * se);
        *(ushort4*)(Cext + (size_t)crow * 4) = w;
    }
}

// ---------------- aggregates: quarter-wave row gathers, butterfly reduce ----------------
// lanes [16q..16q+15] fetch 16B chunks of edge q's row; 4 edges per vmem instr.
// out_node = dinv[node] * (self + sum_edges h'[r]) + bias

__global__ __launch_bounds__(256) void k_agg1(const u16* __restrict__ Hm,
                       const u16* __restrict__ Xp,
                       const int* __restrict__ starts, const u32* __restrict__ ec,
                       const float* __restrict__ dinv,
                       const float* __restrict__ b1, u16* __restrict__ outp) {
    int node = blockIdx.x * (blockDim.x >> 6) + (threadIdx.x >> 6);
    int lane = threadIdx.x & 63;
    if (node >= MPAD) return;
    int c16 = lane & 15;
    u32* orow = (u32*)(outp + (size_t)node * 160);
    if (node >= NN) {              // zero Hcat pad row (finite input for gemm2)
        if (lane < 16) {
            *(uint4*)(orow + c16 * 4) = make_uint4(0, 0, 0, 0);
            orow[64 + lane] = 0;
        }
        return;
    }
    int q = lane >> 4;
    int s = starts[node], e = starts[node + 1];

    float a0=0,a1=0,a2=0,a3=0,a4=0,a5=0,a6=0,a7=0;
    if (lane < 16) {
        uint4 v = *(const uint4*)(Hm + ((size_t)node << 7) + c16 * 8);
        a0 = bflo(v.x); a1 = bfhi(v.x); a2 = bflo(v.y); a3 = bfhi(v.y);
        a4 = bflo(v.z); a5 = bfhi(v.z); a6 = bflo(v.w); a7 = bfhi(v.w);
    }

    for (int g0 = s; g0 < e; g0 += 16) {
        u32 row[4];
#pragma unroll
        for (int grp = 0; grp < 4; ++grp) {
            int idx = g0 + grp * 4 + q;
            int ii = idx < e ? idx : e - 1;
            u32 r = ec[ii];
            row[grp] = (idx < e) ? r : (u32)ZR;
        }
        uint4 v[4];
#pragma unroll
        for (int grp = 0; grp < 4; ++grp)
            v[grp] = *(const uint4*)(Hm + ((size_t)row[grp] << 7) + c16 * 8);
#pragma unroll
        for (int grp = 0; grp < 4; ++grp) {
            a0 += bflo(v[grp].x); a1 += bfhi(v[grp].x);
            a2 += bflo(v[grp].y); a3 += bfhi(v[grp].y);
            a4 += bflo(v[grp].z); a5 += bfhi(v[grp].z);
            a6 += bflo(v[grp].w); a7 += bfhi(v[grp].w);
        }
    }

    // cross-quarter butterfly
    a0 += __shfl_xor(a0, 16); a1 += __shfl_xor(a1, 16);
    a2 += __shfl_xor(a2, 16); a3 += __shfl_xor(a3, 16);
    a4 += __shfl_xor(a4, 16); a5 += __shfl_xor(a5, 16);
    a6 += __shfl_xor(a6, 16); a7 += __shfl_xor(a7, 16);
    a0 += __shfl_xor(a0, 32); a1 += __shfl_xor(a1, 32);
    a2 += __shfl_xor(a2, 32); a3 += __shfl_xor(a3, 32);
    a4 += __shfl_xor(a4, 32); a5 += __shfl_xor(a5, 32);
    a6 += __shfl_xor(a6, 32); a7 += __shfl_xor(a7, 32);

    float dc = dinv[node];
    float4 bA = *(const float4*)(b1 + c16 * 8);
    float4 bB = *(const float4*)(b1 + c16 * 8 + 4);
    float v0 = fmaxf(fmaf(dc, a0, bA.x), 0.f);
    float v1 = fmaxf(fmaf(dc, a1, bA.y), 0.f);
    float v2 = fmaxf(fmaf(dc, a2, bA.z), 0.f);
    float v3 = fmaxf(fmaf(dc, a3, bA.w), 0.f);
    float v4 = fmaxf(fmaf(dc, a4, bB.x), 0.f);
    float v5 = fmaxf(fmaf(dc, a5, bB.y), 0.f);
    float v6 = fmaxf(fmaf(dc, a6, bB.z), 0.f);
    float v7 = fmaxf(fmaf(dc, a7, bB.w), 0.f);

    if (lane < 16) {
        uint4 w = make_uint4(pack2(v0, v1), pack2(v2, v3), pack2(v4, v5), pack2(v6, v7));
        *(uint4*)(orow + c16 * 4) = w;
        orow[64 + lane] = (lane < 2) ? *(const u32*)(Xp + ((size_t)node << 2) + 2 * lane) : 0u;
    }
}

__global__ __launch_bounds__(256) void k_agg2(const u16* __restrict__ Hm,
                       const u16* __restrict__ He,
                       const u16* __restrict__ Xp1,
                       const int* __restrict__ starts, const u32* __restrict__ ec,
                       const float* __restrict__ dinv,
                       const float* __restrict__ b2, float* __restrict__ outp) {
    int node = blockIdx.x * (blockDim.x >> 6) + (threadIdx.x >> 6);
    int lane = threadIdx.x & 63;
    if (node >= NN) return;
    int c16 = lane & 15;
    int q = lane >> 4;
    int s = starts[node], e = starts[node + 1];

    float a0=0,a1=0,a2=0,a3=0,a4=0,a5=0,a6=0,a7=0;
    float cx = 0.f, cy = 0.f;
    if (lane < 16) {
        uint4 v = *(const uint4*)(Hm + ((size_t)node << 7) + c16 * 8);
        a0 = bflo(v.x); a1 = bfhi(v.x); a2 = bflo(v.y); a3 = bfhi(v.y);
        a4 = bflo(v.z); a5 = bfhi(v.z); a6 = bflo(v.w); a7 = bfhi(v.w);
    }
    if (lane < 2) {   // self ext: lane0 cols 128-129, lane1 cols 130-131
        u32 w = *(const u32*)(He + ((size_t)node << 2) + 2 * lane);
        cx = bflo(w); cy = bfhi(w);
    }

    for (int g0 = s; g0 < e; g0 += 16) {
        u32 row[4];
#pragma unroll
        for (int grp = 0; grp < 4; ++grp) {
            int idx = g0 + grp * 4 + q;
            int ii = idx < e ? idx : e - 1;
            u32 r = ec[ii];
            row[grp] = (idx < e) ? r : (u32)ZR;
        }
        uint4 v[4];
#pragma unroll
        for (int grp = 0; grp < 4; ++grp)
            v[grp] = *(const uint4*)(Hm + ((size_t)row[grp] << 7) + c16 * 8);
        // ext cols: lanes with (lane&15)<2 ride their quarter's row record
        if (c16 < 2) {
#pragma unroll
            for (int grp = 0; grp < 4; ++grp) {
                u32 w = *(const u32*)(He + ((size_t)row[grp] << 2) + 2 * (lane & 1));
                cx += bflo(w); cy += bfhi(w);
            }
        }
#pragma unroll
        for (int grp = 0; grp < 4; ++grp) {
            a0 += bflo(v[grp].x); a1 += bfhi(v[grp].x);
            a2 += bflo(v[grp].y); a3 += bfhi(v[grp].y);
            a4 += bflo(v[grp].z); a5 += bfhi(v[grp].z);
            a6 += bflo(v[grp].w); a7 += bfhi(v[grp].w);
        }
    }

    a0 += __shfl_xor(a0, 16); a1 += __shfl_xor(a1, 16);
    a2 += __shfl_xor(a2, 16); a3 += __shfl_xor(a3, 16);
    a4 += __shfl_xor(a4, 16); a5 += __shfl_xor(a5, 16);
    a6 += __shfl_xor(a6, 16); a7 += __shfl_xor(a7, 16);
    cx += __shfl_xor(cx, 16); cy += __shfl_xor(cy, 16);
    a0 += __shfl_xor(a0, 32); a1 += __shfl_xor(a1, 32);
    a2 += __shfl_xor(a2, 32); a3 += __shfl_xor(a3, 32);
    a4 += __shfl_xor(a4, 32); a5 += __shfl_xor(a5, 32);
    a6 += __shfl_xor(a6, 32); a7 += __shfl_xor(a7, 32);
    cx += __shfl_xor(cx, 32); cy += __shfl_xor(cy, 32);

    float dc = dinv[node];
    float* orow = outp + (size_t)node * 136;
    if (lane < 16) {
        float4 bA = *(const float4*)(b2 + c16 * 8);
        float4 bB = *(const float4*)(b2 + c16 * 8 + 4);
        float4 wA, wB;
        wA.x = fmaf(dc, a0, bA.x); wA.y = fmaf(dc, a1, bA.y);
        wA.z = fmaf(dc, a2, bA.z); wA.w = fmaf(dc, a3, bA.w);
        wB.x = fmaf(dc, a4, bB.x); wB.y = fmaf(dc, a5, bB.y);
        wB.z = fmaf(dc, a6, bB.z); wB.w = fmaf(dc, a7, bB.w);
        *(float4*)(orow + c16 * 8) = wA;
        *(float4*)(orow + c16 * 8 + 4) = wB;
    }
    if (lane < 2) {
        float2 bb = *(const float2*)(b2 + 128 + 2 * lane);
        *(float2*)(orow + 128 + 2 * lane) = make_float2(fmaf(dc, cx, bb.x), fmaf(dc, cy, bb.y));
        u32 up = *(const u32*)(Xp1 + ((size_t)node << 2) + 2 * lane);
        *(float2*)(orow + 132 + 2 * lane) = make_float2(bflo(up), bfhi(up));
    }
}

extern "C" void kernel_launch(void* const* d_in, const int* in_sizes, int n_in,
                              void* d_out, int out_size, void* d_ws, size_t ws_size,
                              hipStream_t stream) {
    const int*   ei = (const int*)d_in[0];
    const float* x  = (const float*)d_in[1];
    const float* Wp = (const float*)d_in[2];
    const float* W1 = (const float*)d_in[3];
    const float* b1 = (const float*)d_in[4];
    const float* W2 = (const float*)d_in[5];
    const float* b2 = (const float*)d_in[6];
    float* out = (float*)d_out;

    const int E = in_sizes[0] / 2;
    const int* erow = ei;
    const int* ecol = ei + E;

    // workspace layout
    char* p = (char*)d_ws;
    u16* H1main = (u16*)p; p += (size_t)MPAD * 128 * 2;  // conv1 h' (scaled); reused as H2main
    u16* Hcat   = (u16*)p; p += (size_t)MPAD * 160 * 2;  // h1cat bf16
    u16* Xp1    = (u16*)p; p += (size_t)MPAD * 4 * 2;    // xproj bf16
    u16* H2ext  = (u16*)p; p += (size_t)MPAD * 4 * 2;    // h2' cols 128-131 (scaled)
    u16* W1t    = (u16*)p; p += 144 * 128 * 2;
    u16* W2t    = (u16*)p; p += 144 * 160 * 2;
    u32* recs   = (u32*)p; p += (size_t)E * 4;
    u32* ec     = (u32*)p; p += (size_t)E * 4;
    float* dinv = (float*)p; p += NN * 4;
    int* starts = (int*)p; p += (size_t)(NN + 1) * 4;
    int* gcnt   = (int*)p; p += NB * 4;
    int* gbase  = (int*)p; p += (NB + 1) * 4;
    int* gcursor= (int*)p; p += NB * 4;

    u16* H2main = H1main;

    const int T = 256;
    const int pblocks = (E + PT_TILE - 1) / PT_TILE;

    // weight prep
    k_prep_w1<<<(144 * 128 + T - 1) / T, T, 0, stream>>>(W1, Wp, W1t);
    k_prep_w2<<<(144 * 160 + T - 1) / T, T, 0, stream>>>(W2, W2t);

    // bucketed CSR build
    k_zinit<<<1, 256, 0, stream>>>(gcnt);
    k_bhist<<<pblocks, PT_T, 0, stream>>>(ecol, E, gcnt);
    k_bscan<<<1, 256, 0, stream>>>(gcnt, gbase, gcursor, starts, E);
    k_part<<<pblocks, PT_T, 0, stream>>>(erow, ecol, E, gcursor, recs);
    k_build<<<NB, BT, 0, stream>>>(recs, gbase, starts, dinv, ec);

    const int gblocks = MPAD / 64;
    const int a1blocks = (MPAD + 3) / 4;   // covers pad rows (zeroed)
    const int a2blocks = (NN + 3) / 4;

    // conv1: h' = dinv .* (x @ [W1|Wp]); pad rows = 0
    k_gemm_mfma<128, true, false><<<gblocks, T, 0, stream>>>(x, W1t, dinv, H1main, Xp1);
    k_agg1<<<a1blocks, T, 0, stream>>>(H1main, Xp1, starts, ec, dinv, b1, Hcat);

    // conv2: h2' = dinv .* (h1cat @ W2); pad rows = 0 (incl. ext)
    k_gemm_mfma<160, false, true><<<gblocks, T, 0, stream>>>(Hcat, W2t, dinv, H2main, H2ext);
    k_agg2<<<a2blocks, T, 0, stream>>>(H2main, H2ext, Xp1, starts, ec, dinv, b2, out);
}

// Round 11
// 148.164 us; speedup vs baseline: 8.1742x; 1.0792x over previous
//
#include <hip/hip_runtime.h>

#define NN   50000
#define MPAD 50048   // 782 * 64
#define ZR   NN      // zero-row index (gemm writes zeros there via scale=0)

#define NB    196    // destination buckets: col >> 8
#define SLOTS 48
#define PT_T  512
#define PT_TILE 4096
#define CAP   5888   // fixed per-bucket region capacity (mean 4082, +28 sigma)
#define BT    256

typedef __attribute__((ext_vector_type(8))) short bf16x8;
typedef __attribute__((ext_vector_type(4))) float f32x4;
typedef unsigned int  u32;
typedef unsigned short u16;

__device__ __forceinline__ u16 f2bf(float f) {
    u32 u = __float_as_uint(f);
    return (u16)((u + 0x7fffu + ((u >> 16) & 1u)) >> 16);
}
__device__ __forceinline__ float bflo(u32 u) { return __uint_as_float(u << 16); }
__device__ __forceinline__ float bfhi(u32 u) { return __uint_as_float(u & 0xffff0000u); }
__device__ __forceinline__ u32 pack2(float x, float y) {
    return (u32)f2bf(x) | ((u32)f2bf(y) << 16);
}

// ---------------- fused prep: W1t, W2t bf16 transposes + cursor zeroing ----------------
#define PREP_W1 (144 * 128)
#define PREP_W2 (144 * 160)

__global__ void k_prep(const float* __restrict__ W1, const float* __restrict__ Wp,
                       const float* __restrict__ W2,
                       u16* __restrict__ W1t, u16* __restrict__ W2t,
                       int* __restrict__ gcursor) {
    int i = blockIdx.x * blockDim.x + threadIdx.x;
    if (i < PREP_W1) {
        int n = i >> 7, k = i & 127;
        float v = 0.f;
        if (n < 128) v = W1[k * 128 + n];
        else if (n < 132) v = Wp[k * 4 + (n - 128)];
        W1t[i] = f2bf(v);
        return;
    }
    i -= PREP_W1;
    if (i < PREP_W2) {
        int n = i / 160, k = i - n * 160;
        float v = (n < 132 && k < 132) ? W2[k * 132 + n] : 0.f;
        W2t[i] = f2bf(v);
        return;
    }
    i -= PREP_W2;
    if (i < NB) gcursor[i] = 0;
}

// ---------------- partition: direct append into fixed-capacity bucket regions ----------------
// rec = (col&255)<<24 | row
__global__ __launch_bounds__(PT_T) void k_part(const int* __restrict__ erow,
                                               const int* __restrict__ ecol, int E,
                                               int* __restrict__ gcursor,
                                               u32* __restrict__ recs) {
    __shared__ int lcnt[NB];
    __shared__ int bbase[NB];
    __shared__ u32 rbuf[NB * SLOTS];
    int tid = threadIdx.x;
    for (int i = tid; i < NB; i += PT_T) lcnt[i] = 0;
    __syncthreads();
    int e0 = blockIdx.x * PT_TILE;
#pragma unroll
    for (int j = 0; j < PT_TILE / PT_T; ++j) {
        int e = e0 + j * PT_T + tid;
        if (e < E) {
            int c = ecol[e];
            u32 rec = ((u32)(c & 255) << 24) | (u32)erow[e];
            int b = c >> 8;
            int pos = atomicAdd(&lcnt[b], 1);
            if (pos < SLOTS) rbuf[b * SLOTS + pos] = rec;
            else {  // staging overflow: direct global emit
                int g = atomicAdd(&gcursor[b], 1);
                if (g < CAP) recs[(size_t)b * CAP + g] = rec;
            }
        }
    }
    __syncthreads();
    if (tid < NB) {
        int n = lcnt[tid]; if (n > SLOTS) n = SLOTS;
        bbase[tid] = n ? atomicAdd(&gcursor[tid], n) : 0;
    }
    __syncthreads();
    int wave = tid >> 6, lane = tid & 63;
    for (int b = wave; b < NB; b += PT_T / 64) {
        int n = lcnt[b]; if (n > SLOTS) n = SLOTS;
        if (lane < n) {
            int g = bbase[b] + lane;
            if (g < CAP) recs[(size_t)b * CAP + g] = rbuf[b * SLOTS + lane];
        }
    }
}

// 1 block: exclusive scan of clamped bucket counts -> gbase[NB+1]; starts[NN]=total
__global__ void k_bscan(const int* __restrict__ gcursor, int* __restrict__ gbase,
                        int* __restrict__ starts) {
    __shared__ int a[256];
    int tid = threadIdx.x;
    int c = (tid < NB) ? gcursor[tid] : 0;
    if (c > CAP) c = CAP;
    a[tid] = c;
    __syncthreads();
    for (int off = 1; off < 256; off <<= 1) {
        int add = (tid >= off) ? a[tid - off] : 0;
        __syncthreads();
        a[tid] += add;
        __syncthreads();
    }
    if (tid < NB) gbase[tid] = a[tid] - c;
    if (tid == NB - 1) { gbase[NB] = a[tid]; starts[NN] = a[tid]; }
}

// per-bucket: count -> scan -> starts/dinv -> LDS scatter -> coalesced compacted out
__global__ __launch_bounds__(BT) void k_build(const u32* __restrict__ recs,
                                              const int* __restrict__ gbase,
                                              int* __restrict__ starts,
                                              float* __restrict__ dinv,
                                              u32* __restrict__ ec) {
    __shared__ u32 rbuf[CAP];
    __shared__ u32 obuf[CAP];
    __shared__ int ncnt[256];
    __shared__ int a[256];
    __shared__ int ncur[256];
    int tid = threadIdx.x, b = blockIdx.x;
    int lo = gbase[b], hi = gbase[b + 1];
    int cnt = hi - lo;                       // <= CAP by construction
    const u32* src = recs + (size_t)b * CAP;
    for (int i = tid; i < cnt; i += BT) rbuf[i] = src[i];
    ncnt[tid] = 0;
    __syncthreads();
    for (int i = tid; i < cnt; i += BT) atomicAdd(&ncnt[rbuf[i] >> 24], 1);
    __syncthreads();
    a[tid] = ncnt[tid];
    __syncthreads();
    for (int off = 1; off < 256; off <<= 1) {
        int add = (tid >= off) ? a[tid - off] : 0;
        __syncthreads();
        a[tid] += add;
        __syncthreads();
    }
    int excl = a[tid] - ncnt[tid];
    ncur[tid] = excl;
    {
        int node = (b << 8) + tid;
        if (node < NN) {
            starts[node] = lo + excl;
            float d = (float)ncnt[tid] + 1.0f;
            dinv[node] = rsqrtf(d);
        }
    }
    __syncthreads();
    for (int i = tid; i < cnt; i += BT) {
        u32 rec = rbuf[i];
        int pos = atomicAdd(&ncur[rec >> 24], 1);
        if (pos >= 0 && pos < CAP) obuf[pos] = rec & 0xFFFFFFu;
    }
    __syncthreads();
    for (int i = tid; i < cnt; i += BT) ec[lo + i] = obuf[i];
}

// ---------------- MFMA GEMM, fused dinv row-scaling; pad rows scale=0 -> zeros ----------------
template<int K, bool CONVF32, bool SCALE_EXT>
__global__ __launch_bounds__(256) void k_gemm_mfma(const void* __restrict__ Ain,
                                                   const u16* __restrict__ Bt,
                                                   const float* __restrict__ rs,
                                                   u16* __restrict__ Cmain,
                                                   u16* __restrict__ Cext) {
    int lane = threadIdx.x & 63;
    int wv = threadIdx.x >> 6;
    int rbase = blockIdx.x * 64 + wv * 16;
    int lr = lane & 15;
    int kk = (lane >> 4) * 8;
    int arow = rbase + lr;
    if (CONVF32 && arow >= NN) arow = NN - 1;

    const u16* bp = Bt + (size_t)lr * K + kk;

    f32x4 acc[9] = {};
#pragma unroll
    for (int ks = 0; ks < K / 32; ++ks) {
        bf16x8 af;
        if (CONVF32) {
            const float* ap = (const float*)Ain + (size_t)arow * K + kk + ks * 32;
            float4 f0 = *(const float4*)ap;
            float4 f1 = *(const float4*)(ap + 4);
            union { uint4 u; bf16x8 v; } cv;
            cv.u.x = pack2(f0.x, f0.y); cv.u.y = pack2(f0.z, f0.w);
            cv.u.z = pack2(f1.x, f1.y); cv.u.w = pack2(f1.z, f1.w);
            af = cv.v;
        } else {
            af = *(const bf16x8*)((const u16*)Ain + (size_t)arow * K + kk + ks * 32);
        }
#pragma unroll
        for (int t = 0; t < 9; ++t) {
            bf16x8 bf = *(const bf16x8*)(bp + (size_t)(t * 16) * K + ks * 32);
            acc[t] = __builtin_amdgcn_mfma_f32_16x16x32_bf16(bf, af, acc[t], 0, 0, 0);
        }
    }

    int n0 = (lane >> 4) * 4;
    int crow = rbase + lr;
    float s = (crow < NN) ? rs[crow] : 0.0f;   // pad rows -> exact zeros
    u16* cm = Cmain + (size_t)crow * 128;
#pragma unroll
    for (int t = 0; t < 8; ++t) {
        ushort4 w;
        w.x = f2bf(acc[t][0] * s); w.y = f2bf(acc[t][1] * s);
        w.z = f2bf(acc[t][2] * s); w.w = f2bf(acc[t][3] * s);
        *(ushort4*)(cm + 16 * t + n0) = w;
    }
    if (n0 == 0) {
        float se = SCALE_EXT ? s : ((crow < NN) ? 1.0f : 0.0f);
        ushort4 w;
        w.x = f2bf(acc[8][0] * se); w.y = f2bf(acc[8][1] * se);
        w.z = f2bf(acc[8][2] * se); w.w = f2bf(acc[8][3] * se);
        *(ushort4*)(Cext + (size_t)crow * 4) = w;
    }
}

// ---------------- aggregates: quarter-wave row gathers, butterfly reduce ----------------

__global__ __launch_bounds__(256) void k_agg1(const u16* __restrict__ Hm,
                       const u16* __restrict__ Xp,
                       const int* __restrict__ starts, const u32* __restrict__ ec,
                       const float* __restrict__ dinv,
                       const float* __restrict__ b1, u16* __restrict__ outp) {
    int node = blockIdx.x * (blockDim.x >> 6) + (threadIdx.x >> 6);
    int lane = threadIdx.x & 63;
    if (node >= MPAD) return;
    int c16 = lane & 15;
    u32* orow = (u32*)(outp + (size_t)node * 160);
    if (node >= NN) {              // zero Hcat pad row
        if (lane < 16) {
            *(uint4*)(orow + c16 * 4) = make_uint4(0, 0, 0, 0);
            orow[64 + lane] = 0;
        }
        return;
    }
    int q = lane >> 4;
    int s = starts[node], e = starts[node + 1];

    float a0=0,a1=0,a2=0,a3=0,a4=0,a5=0,a6=0,a7=0;
    if (lane < 16) {
        uint4 v = *(const uint4*)(Hm + ((size_t)node << 7) + c16 * 8);
        a0 = bflo(v.x); a1 = bfhi(v.x); a2 = bflo(v.y); a3 = bfhi(v.y);
        a4 = bflo(v.z); a5 = bfhi(v.z); a6 = bflo(v.w); a7 = bfhi(v.w);
    }

    for (int g0 = s; g0 < e; g0 += 16) {
        u32 row[4];
#pragma unroll
        for (int grp = 0; grp < 4; ++grp) {
            int idx = g0 + grp * 4 + q;
            int ii = idx < e ? idx : e - 1;
            u32 r = ec[ii];
            row[grp] = (idx < e) ? r : (u32)ZR;
        }
        uint4 v[4];
#pragma unroll
        for (int grp = 0; grp < 4; ++grp)
            v[grp] = *(const uint4*)(Hm + ((size_t)row[grp] << 7) + c16 * 8);
#pragma unroll
        for (int grp = 0; grp < 4; ++grp) {
            a0 += bflo(v[grp].x); a1 += bfhi(v[grp].x);
            a2 += bflo(v[grp].y); a3 += bfhi(v[grp].y);
            a4 += bflo(v[grp].z); a5 += bfhi(v[grp].z);
            a6 += bflo(v[grp].w); a7 += bfhi(v[grp].w);
        }
    }

    a0 += __shfl_xor(a0, 16); a1 += __shfl_xor(a1, 16);
    a2 += __shfl_xor(a2, 16); a3 += __shfl_xor(a3, 16);
    a4 += __shfl_xor(a4, 16); a5 += __shfl_xor(a5, 16);
    a6 += __shfl_xor(a6, 16); a7 += __shfl_xor(a7, 16);
    a0 += __shfl_xor(a0, 32); a1 += __shfl_xor(a1, 32);
    a2 += __shfl_xor(a2, 32); a3 += __shfl_xor(a3, 32);
    a4 += __shfl_xor(a4, 32); a5 += __shfl_xor(a5, 32);
    a6 += __shfl_xor(a6, 32); a7 += __shfl_xor(a7, 32);

    float dc = dinv[node];
    float4 bA = *(const float4*)(b1 + c16 * 8);
    float4 bB = *(const float4*)(b1 + c16 * 8 + 4);
    float v0 = fmaxf(fmaf(dc, a0, bA.x), 0.f);
    float v1 = fmaxf(fmaf(dc, a1, bA.y), 0.f);
    float v2 = fmaxf(fmaf(dc, a2, bA.z), 0.f);
    float v3 = fmaxf(fmaf(dc, a3, bA.w), 0.f);
    float v4 = fmaxf(fmaf(dc, a4, bB.x), 0.f);
    float v5 = fmaxf(fmaf(dc, a5, bB.y), 0.f);
    float v6 = fmaxf(fmaf(dc, a6, bB.z), 0.f);
    float v7 = fmaxf(fmaf(dc, a7, bB.w), 0.f);

    if (lane < 16) {
        uint4 w = make_uint4(pack2(v0, v1), pack2(v2, v3), pack2(v4, v5), pack2(v6, v7));
        *(uint4*)(orow + c16 * 4) = w;
        orow[64 + lane] = (lane < 2) ? *(const u32*)(Xp + ((size_t)node << 2) + 2 * lane) : 0u;
    }
}

__global__ __launch_bounds__(256) void k_agg2(const u16* __restrict__ Hm,
                       const u16* __restrict__ He,
                       const u16* __restrict__ Xp1,
                       const int* __restrict__ starts, const u32* __restrict__ ec,
                       const float* __restrict__ dinv,
                       const float* __restrict__ b2, float* __restrict__ outp) {
    int node = blockIdx.x * (blockDim.x >> 6) + (threadIdx.x >> 6);
    int lane = threadIdx.x & 63;
    if (node >= NN) return;
    int c16 = lane & 15;
    int q = lane >> 4;
    int s = starts[node], e = starts[node + 1];

    float a0=0,a1=0,a2=0,a3=0,a4=0,a5=0,a6=0,a7=0;
    float cx = 0.f, cy = 0.f;
    if (lane < 16) {
        uint4 v = *(const uint4*)(Hm + ((size_t)node << 7) + c16 * 8);
        a0 = bflo(v.x); a1 = bfhi(v.x); a2 = bflo(v.y); a3 = bfhi(v.y);
        a4 = bflo(v.z); a5 = bfhi(v.z); a6 = bflo(v.w); a7 = bfhi(v.w);
    }
    if (lane < 2) {
        u32 w = *(const u32*)(He + ((size_t)node << 2) + 2 * lane);
        cx = bflo(w); cy = bfhi(w);
    }

    for (int g0 = s; g0 < e; g0 += 16) {
        u32 row[4];
#pragma unroll
        for (int grp = 0; grp < 4; ++grp) {
            int idx = g0 + grp * 4 + q;
            int ii = idx < e ? idx : e - 1;
            u32 r = ec[ii];
            row[grp] = (idx < e) ? r : (u32)ZR;
        }
        uint4 v[4];
#pragma unroll
        for (int grp = 0; grp < 4; ++grp)
            v[grp] = *(const uint4*)(Hm + ((size_t)row[grp] << 7) + c16 * 8);
        if (c16 < 2) {
#pragma unroll
            for (int grp = 0; grp < 4; ++grp) {
                u32 w = *(const u32*)(He + ((size_t)row[grp] << 2) + 2 * (lane & 1));
                cx += bflo(w); cy += bfhi(w);
            }
        }
#pragma unroll
        for (int grp = 0; grp < 4; ++grp) {
            a0 += bflo(v[grp].x); a1 += bfhi(v[grp].x);
            a2 += bflo(v[grp].y); a3 += bfhi(v[grp].y);
            a4 += bflo(v[grp].z); a5 += bfhi(v[grp].z);
            a6 += bflo(v[grp].w); a7 += bfhi(v[grp].w);
        }
    }

    a0 += __shfl_xor(a0, 16); a1 += __shfl_xor(a1, 16);
    a2 += __shfl_xor(a2, 16); a3 += __shfl_xor(a3, 16);
    a4 += __shfl_xor(a4, 16); a5 += __shfl_xor(a5, 16);
    a6 += __shfl_xor(a6, 16); a7 += __shfl_xor(a7, 16);
    cx += __shfl_xor(cx, 16); cy += __shfl_xor(cy, 16);
    a0 += __shfl_xor(a0, 32); a1 += __shfl_xor(a1, 32);
    a2 += __shfl_xor(a2, 32); a3 += __shfl_xor(a3, 32);
    a4 += __shfl_xor(a4, 32); a5 += __shfl_xor(a5, 32);
    a6 += __shfl_xor(a6, 32); a7 += __shfl_xor(a7, 32);
    cx += __shfl_xor(cx, 32); cy += __shfl_xor(cy, 32);

    float dc = dinv[node];
    float* orow = outp + (size_t)node * 136;
    if (lane < 16) {
        float4 bA = *(const float4*)(b2 + c16 * 8);
        float4 bB = *(const float4*)(b2 + c16 * 8 + 4);
        float4 wA, wB;
        wA.x = fmaf(dc, a0, bA.x); wA.y = fmaf(dc, a1, bA.y);
        wA.z = fmaf(dc, a2, bA.z); wA.w = fmaf(dc, a3, bA.w);
        wB.x = fmaf(dc, a4, bB.x); wB.y = fmaf(dc, a5, bB.y);
        wB.z = fmaf(dc, a6, bB.z); wB.w = fmaf(dc, a7, bB.w);
        *(float4*)(orow + c16 * 8) = wA;
        *(float4*)(orow + c16 * 8 + 4) = wB;
    }
    if (lane < 2) {
        float2 bb = *(const float2*)(b2 + 128 + 2 * lane);
        *(float2*)(orow + 128 + 2 * lane) = make_float2(fmaf(dc, cx, bb.x), fmaf(dc, cy, bb.y));
        u32 up = *(const u32*)(Xp1 + ((size_t)node << 2) + 2 * lane);
        *(float2*)(orow + 132 + 2 * lane) = make_float2(bflo(up), bfhi(up));
    }
}

extern "C" void kernel_launch(void* const* d_in, const int* in_sizes, int n_in,
                              void* d_out, int out_size, void* d_ws, size_t ws_size,
                              hipStream_t stream) {
    const int*   ei = (const int*)d_in[0];
    const float* x  = (const float*)d_in[1];
    const float* Wp = (const float*)d_in[2];
    const float* W1 = (const float*)d_in[3];
    const float* b1 = (const float*)d_in[4];
    const float* W2 = (const float*)d_in[5];
    const float* b2 = (const float*)d_in[6];
    float* out = (float*)d_out;

    const int E = in_sizes[0] / 2;
    const int* erow = ei;
    const int* ecol = ei + E;

    // workspace layout
    char* p = (char*)d_ws;
    u16* H1main = (u16*)p; p += (size_t)MPAD * 128 * 2;  // conv1 h' (scaled); reused as H2main
    u16* Hcat   = (u16*)p; p += (size_t)MPAD * 160 * 2;  // h1cat bf16
    u16* Xp1    = (u16*)p; p += (size_t)MPAD * 4 * 2;    // xproj bf16
    u16* H2ext  = (u16*)p; p += (size_t)MPAD * 4 * 2;    // h2' cols 128-131 (scaled)
    u16* W1t    = (u16*)p; p += 144 * 128 * 2;
    u16* W2t    = (u16*)p; p += 144 * 160 * 2;
    u32* recs   = (u32*)p; p += (size_t)NB * CAP * 4;    // fixed-capacity bucket regions
    u32* ec     = (u32*)p; p += (size_t)E * 4;           // compacted row-only records
    float* dinv = (float*)p; p += NN * 4;
    int* starts = (int*)p; p += (size_t)(NN + 1) * 4;
    int* gbase  = (int*)p; p += (NB + 1) * 4;
    int* gcursor= (int*)p; p += NB * 4;

    u16* H2main = H1main;

    const int T = 256;
    const int pblocks = (E + PT_TILE - 1) / PT_TILE;

    // fused prep (weights + cursor zero)
    const int prep_total = PREP_W1 + PREP_W2 + NB;
    k_prep<<<(prep_total + T - 1) / T, T, 0, stream>>>(W1, Wp, W2, W1t, W2t, gcursor);

    // CSR build: partition -> scan -> build  (3 dispatches)
    k_part<<<pblocks, PT_T, 0, stream>>>(erow, ecol, E, gcursor, recs);
    k_bscan<<<1, 256, 0, stream>>>(gcursor, gbase, starts);
    k_build<<<NB, BT, 0, stream>>>(recs, gbase, starts, dinv, ec);

    const int gblocks = MPAD / 64;
    const int a1blocks = (MPAD + 3) / 4;
    const int a2blocks = (NN + 3) / 4;

    // conv1: h' = dinv .* (x @ [W1|Wp]); pad rows = 0
    k_gemm_mfma<128, true, false><<<gblocks, T, 0, stream>>>(x, W1t, dinv, H1main, Xp1);
    k_agg1<<<a1blocks, T, 0, stream>>>(H1main, Xp1, starts, ec, dinv, b1, Hcat);

    // conv2: h2' = dinv .* (h1cat @ W2); pad rows = 0 (incl. ext)
    k_gemm_mfma<160, false, true><<<gblocks, T, 0, stream>>>(Hcat, W2t, dinv, H2main, H2ext);
    k_agg2<<<a2blocks, T, 0, stream>>>(H2main, H2ext, Xp1, starts, ec, dinv, b2, out);
}